// Round 11
// baseline (780.038 us; speedup 1.0000x reference)
//
#include <hip/hip_runtime.h>

// ---------------------------------------------------------------------------
// Part_65712999629561: ParticleTransformer forward, N=2048, P=64, E=32, H=4,
// D=8. Kernels: stats x2, embed(feat+conv+BN+e1+e2), 4x layer, cls.
// R10 post-mortem: neutral — GEMMs are DS-pipe-bound (8 ds_read_b128/iter vs
// 64 FMA; DS pipe 2x oversubscribed at 12 waves/CU).
// R11: weight reads moved to global/L2 (weights shared by all blocks); SW
// staging + array deleted -> LDS ~35KB -> 4 blocks/CU (launch_bounds(256,4)).
// DS pipe now carries only activations + attention k/v.
// ---------------------------------------------------------------------------

__device__ __forceinline__ float4 ld4(const float* p){ return *reinterpret_cast<const float4*>(p); }
__device__ __forceinline__ void st4(float* p, float4 v){ *reinterpret_cast<float4*>(p) = v; }
__device__ __forceinline__ float dot4(float4 a, float4 b){ return a.x*b.x + a.y*b.y + a.z*b.z + a.w*b.w; }
__device__ __forceinline__ float geluf(float v){ return 0.5f*v*(1.0f + erff(v*0.70710678118654752f)); }

// ---------------- Kernel A: batchnorm stats --------------------------------
__global__ void bn_stats_partial(const float* __restrict__ x, const float* __restrict__ fm,
                                 float* __restrict__ part) {
  int p  = threadIdx.x & 63;
  int rg = threadIdx.x >> 6;
  float s = 0.f, s2 = 0.f;
  for (int R = blockIdx.x*4 + rg; R < 2048*64; R += 1024) {
    int n_ = R >> 6, c = R & 63;
    float v = (c < 60) ? x[n_*3840 + c*64 + p] : fm[n_*256 + (c-60)*64 + p];
    s += v; s2 += v*v;
  }
  __shared__ float sm[256], sm2[256];
  sm[threadIdx.x] = s; sm2[threadIdx.x] = s2;
  __syncthreads();
  if (threadIdx.x < 64) {
    part[blockIdx.x*128 + p]      = sm[p]+sm[64+p]+sm[128+p]+sm[192+p];
    part[blockIdx.x*128 + 64 + p] = sm2[p]+sm2[64+p]+sm2[128+p]+sm2[192+p];
  }
}

__global__ void bn_stats_final(const float* __restrict__ part, float* __restrict__ stats) {
  int p = threadIdx.x; // 64 threads
  float s = 0.f, s2 = 0.f;
  for (int b = 0; b < 256; b++){ s += part[b*128+p]; s2 += part[b*128+64+p]; }
  float mean = s * (1.f/131072.f);
  float var  = s2 * (1.f/131072.f) - mean*mean;
  stats[p]      = mean;
  stats[64+p]   = rsqrtf(var + 1e-5f);
}

// ---------------- row-LN helpers (vectorized, 64 rows, 4 lanes/row) --------
__device__ __forceinline__ void ln_rows32(const float* src, float* dst, int tid){
  int r = tid>>2, g = tid&3;
  const float* row = src + r*36 + g*8;
  float4 a = ld4(row), b = ld4(row+4);
  float s = a.x+a.y+a.z+a.w + b.x+b.y+b.z+b.w;
  s += __shfl_xor(s,1); s += __shfl_xor(s,2);
  float mean = s * 0.03125f;
  float4 da = make_float4(a.x-mean,a.y-mean,a.z-mean,a.w-mean);
  float4 db = make_float4(b.x-mean,b.y-mean,b.z-mean,b.w-mean);
  float q = dot4(da,da) + dot4(db,db);
  q += __shfl_xor(q,1); q += __shfl_xor(q,2);
  float irs = rsqrtf(q*0.03125f + 1e-5f);
  float* drow = dst + r*36 + g*8;
  st4(drow,   make_float4(da.x*irs, da.y*irs, da.z*irs, da.w*irs));
  st4(drow+4, make_float4(db.x*irs, db.y*irs, db.z*irs, db.w*irs));
}

__device__ __forceinline__ void ln_rows64(const float* src, float* dst, int tid){
  int r = tid>>2, g = tid&3;
  const float* row = src + r*68 + g*16;
  float4 v0 = ld4(row), v1 = ld4(row+4), v2 = ld4(row+8), v3 = ld4(row+12);
  float s = v0.x+v0.y+v0.z+v0.w + v1.x+v1.y+v1.z+v1.w
          + v2.x+v2.y+v2.z+v2.w + v3.x+v3.y+v3.z+v3.w;
  s += __shfl_xor(s,1); s += __shfl_xor(s,2);
  float mean = s * 0.015625f;
  float4 d0 = make_float4(v0.x-mean,v0.y-mean,v0.z-mean,v0.w-mean);
  float4 d1 = make_float4(v1.x-mean,v1.y-mean,v1.z-mean,v1.w-mean);
  float4 d2 = make_float4(v2.x-mean,v2.y-mean,v2.z-mean,v2.w-mean);
  float4 d3 = make_float4(v3.x-mean,v3.y-mean,v3.z-mean,v3.w-mean);
  float q = dot4(d0,d0)+dot4(d1,d1)+dot4(d2,d2)+dot4(d3,d3);
  q += __shfl_xor(q,1); q += __shfl_xor(q,2);
  float irs = rsqrtf(q*0.015625f + 1e-5f);
  float* drow = dst + r*68 + g*16;
  st4(drow,    make_float4(d0.x*irs,d0.y*irs,d0.z*irs,d0.w*irs));
  st4(drow+4,  make_float4(d1.x*irs,d1.y*irs,d1.z*irs,d1.w*irs));
  st4(drow+8,  make_float4(d2.x*irs,d2.y*irs,d2.z*irs,d2.w*irs));
  st4(drow+12, make_float4(d3.x*irs,d3.y*irs,d3.z*irs,d3.w*irs));
}

// ============================ K_embed ======================================
// feat(conv1+conv2 -> G_bias) + BN-apply + ln + e1 + ln + e2 -> G_h.
__global__ __launch_bounds__(256, 4) void k_embed(
    const float* __restrict__ x, const float* __restrict__ fm,
    const float* __restrict__ stats,
    const float* __restrict__ bn_w, const float* __restrict__ bn_b,
    const float* __restrict__ e1w, const float* __restrict__ e1b,
    const float* __restrict__ e2w, const float* __restrict__ e2b,
    const float* __restrict__ c1w_g, const float* __restrict__ c1b_g,
    const float* __restrict__ c2w_g, const float* __restrict__ c2b_g,
    float* __restrict__ G_h, float* __restrict__ G_bias)
{
  const int n   = blockIdx.x;
  const int tid = threadIdx.x;

  __shared__ __align__(16) float SX[64*68];
  __shared__ __align__(16) float SY[64*68];   // scratch: PQ@0[448], C1O@448[1024], CW@1472[328]
  __shared__ float SSTAT[128];

  float* PQ  = SY;
  float* C1O = SY + 448;
  float* CW  = SY + 1472;

  if (tid < 64) {
    float mu = stats[tid], rs = stats[64+tid];
    float sc = rs * bn_w[tid];
    SSTAT[tid]      = sc;
    SSTAT[64+tid]   = bn_b[tid] - mu*sc;
  }
  if (tid < 64) {
    int p = tid;
    float e_  = fm[n*256 + p];
    float px_ = fm[n*256 + 64 + p];
    float py_ = fm[n*256 + 128 + p];
    float pz_ = fm[n*256 + 192 + p];
    float pt_ = sqrtf(px_*px_ + py_*py_ + 1e-8f);
    float y_  = 0.5f * logf((e_ + pz_ + 1e-8f) / (e_ - pz_ + 1e-8f));
    float ph_ = atan2f(py_, px_ + 1e-8f);
    if (ph_ < 0.f) ph_ += 6.283185307179586f;
    PQ[0*64+p]=e_; PQ[1*64+p]=px_; PQ[2*64+p]=py_; PQ[3*64+p]=pz_;
    PQ[4*64+p]=pt_; PQ[5*64+p]=y_; PQ[6*64+p]=ph_;
  }
  CW[tid] = c1w_g[tid];
  if (tid < 4)  CW[256+tid] = c1b_g[tid];
  if (tid < 64) CW[260+tid] = c2w_g[tid];
  if (tid < 4)  CW[324+tid] = c2b_g[tid];
  __syncthreads();

  // conv1 (stride4, k4) -> C1O [4][16][16]
  {
    int ho = tid>>4, wo = tid&15;
    float a0=0.f,a1=0.f,a2=0.f,a3=0.f;
    #pragma unroll 1
    for (int kh=0; kh<4; kh++){
      int r = ho*4+kh;
      float er=PQ[r], pxr=PQ[64+r], pyr=PQ[128+r], pzr=PQ[192+r], ptr_=PQ[256+r], yr=PQ[320+r], phr=PQ[384+r];
      #pragma unroll
      for (int kw=0; kw<4; kw++){
        int c = wo*4+kw;
        if (r == c) continue;
        float ec=PQ[c], pxc=PQ[64+c], pyc=PQ[128+c], pzc=PQ[192+c], ptc=PQ[256+c], yc=PQ[320+c], phc=PQ[384+c];
        float dy = yr-yc, dp = phr-phc;
        float delta = sqrtf(fabsf(dy*dy + dp*dp));
        float pmin = fminf(ptr_, ptc);
        float kt = pmin * delta;
        float zz = pmin / (ptr_ + ptc + 1e-8f);
        float sx_ = pxr+pxc, sy_ = pyr+pyc, sz_ = pzr+pzc;
        float m2 = er*er + ec*ec - (sx_*sx_ + sy_*sy_ + sz_*sz_);
        int wb = kh*4+kw;
        a0 += delta*CW[0*64+wb] + kt*CW[0*64+16+wb] + zz*CW[0*64+32+wb] + m2*CW[0*64+48+wb];
        a1 += delta*CW[1*64+wb] + kt*CW[1*64+16+wb] + zz*CW[1*64+32+wb] + m2*CW[1*64+48+wb];
        a2 += delta*CW[2*64+wb] + kt*CW[2*64+16+wb] + zz*CW[2*64+32+wb] + m2*CW[2*64+48+wb];
        a3 += delta*CW[3*64+wb] + kt*CW[3*64+16+wb] + zz*CW[3*64+32+wb] + m2*CW[3*64+48+wb];
      }
    }
    C1O[0*256 + tid] = a0 + CW[256+0];
    C1O[1*256 + tid] = a1 + CW[256+1];
    C1O[2*256 + tid] = a2 + CW[256+2];
    C1O[3*256 + tid] = a3 + CW[256+3];
  }
  __syncthreads();

  // conv2 -> G_bias; BN-apply stage xc -> SX
  for (int idx = tid; idx < 324; idx += 256) {
    int co = idx/81, rem = idx%81, i = rem/9, j = rem%9;
    float s = CW[324+co];
    #pragma unroll
    for (int ci=0; ci<4; ci++){
      #pragma unroll
      for (int kh=0; kh<2; kh++){
        int ri = 2*i - 1 + kh;
        if (ri < 0 || ri >= 16) continue;
        #pragma unroll
        for (int kw=0; kw<2; kw++){
          int cj = 2*j - 1 + kw;
          if (cj < 0 || cj >= 16) continue;
          s += CW[260 + co*16 + ci*4 + kh*2 + kw] * C1O[ci*256 + ri*16 + cj];
        }
      }
    }
    G_bias[n*324 + idx] = s;
  }
  {
    int p4 = (tid & 15) * 4;
    float sc0 = SSTAT[p4], sc1 = SSTAT[p4+1], sc2 = SSTAT[p4+2], sc3 = SSTAT[p4+3];
    float sh0 = SSTAT[64+p4], sh1 = SSTAT[64+p4+1], sh2 = SSTAT[64+p4+2], sh3 = SSTAT[64+p4+3];
    for (int c = tid>>4; c < 64; c += 16) {
      float4 v = (c < 60) ? ld4(x + n*3840 + c*64 + p4) : ld4(fm + n*256 + (c-60)*64 + p4);
      st4(&SX[c*68 + p4], make_float4(v.x*sc0+sh0, v.y*sc1+sh1, v.z*sc2+sh2, v.w*sc3+sh3));
    }
  }
  __syncthreads();

  ln_rows64(SX, SY, tid);   // SY = ln(xc) (overwrites conv scratch)
  __syncthreads();

  // e1 GEMM 64x64 K=64, 4x4 tile (outputs o*16+og) -> SX (stride 68) + gelu
  // weights straight from global (L2-hot; row stride 64)
  {
    int tg = tid>>4, og = tid&15;
    float acc[4][4];
    #pragma unroll
    for (int o=0;o<4;o++){ float b = e1b[o*16+og];
      #pragma unroll
      for (int i=0;i<4;i++) acc[i][o] = b; }
    #pragma unroll 2
    for (int j=0;j<64;j+=4){
      float4 av[4], wv[4];
      #pragma unroll
      for (int i=0;i<4;i++) av[i] = ld4(SY + (tg*4+i)*68 + j);
      #pragma unroll
      for (int o=0;o<4;o++) wv[o] = ld4(e1w + (o*16+og)*64 + j);
      #pragma unroll
      for (int i=0;i<4;i++)
        #pragma unroll
        for (int o=0;o<4;o++) acc[i][o] += dot4(av[i], wv[o]);
    }
    __syncthreads();   // SY reads + prior SX reads done
    #pragma unroll
    for (int i=0;i<4;i++)
      #pragma unroll
      for (int o=0;o<4;o++) SX[(tg*4+i)*68 + o*16+og] = geluf(acc[i][o]);
  }
  __syncthreads();

  ln_rows64(SX, SY, tid);
  __syncthreads();

  // e2 GEMM 64x32 K=64, 4x2 tile (outputs o*16+og) -> G_h + gelu
  {
    int tg = tid>>4, og = tid&15;
    float acc[4][2];
    #pragma unroll
    for (int o=0;o<2;o++){ float b = e2b[o*16+og];
      #pragma unroll
      for (int i=0;i<4;i++) acc[i][o] = b; }
    #pragma unroll 2
    for (int j=0;j<64;j+=4){
      float4 av[4], wv[2];
      #pragma unroll
      for (int i=0;i<4;i++) av[i] = ld4(SY + (tg*4+i)*68 + j);
      #pragma unroll
      for (int o=0;o<2;o++) wv[o] = ld4(e2w + (o*16+og)*64 + j);
      #pragma unroll
      for (int i=0;i<4;i++)
        #pragma unroll
        for (int o=0;o<2;o++) acc[i][o] += dot4(av[i], wv[o]);
    }
    #pragma unroll
    for (int i=0;i<4;i++)
      #pragma unroll
      for (int o=0;o<2;o++) G_h[n*2048 + (tg*4+i)*32 + o*16+og] = geluf(acc[i][o]);
  }
}

// ============================ K_layer ======================================
__global__ __launch_bounds__(256, 4) void k_layer(
    const int* __restrict__ ji,
    const float* __restrict__ in_w,  const float* __restrict__ in_b,
    const float* __restrict__ out_w, const float* __restrict__ out_b,
    const float* __restrict__ f1w,   const float* __restrict__ f1b,
    const float* __restrict__ f2w,   const float* __restrict__ f2b,
    const float* __restrict__ wres,
    float* __restrict__ G_h, const float* __restrict__ G_bias)
{
  const int n   = blockIdx.x;
  const int tid = threadIdx.x;

  __shared__ __align__(16) float SH[64*36];
  __shared__ __align__(16) float SX[64*36];
  __shared__ __align__(16) float SY[64*68];
  __shared__ int s_njet;

  if (tid == 0) s_njet = ji[n*2+1];
  float b9[9];
  {
    int hh = tid>>6, l = tid&63;
    if (l < 9) {
      #pragma unroll
      for (int j=0;j<9;j++) b9[j] = G_bias[n*324 + hh*81 + l*9 + j];
    } else {
      #pragma unroll
      for (int j=0;j<9;j++) b9[j] = 0.f;
    }
  }
  for (int idx = tid; idx < 512; idx += 256) {
    float4 v = ld4(G_h + n*2048 + idx*4);
    int t = idx>>3, e = (idx&7)*4;
    st4(&SH[t*36 + e], v);
  }
  __syncthreads();

  // L1: a = ln(h) -> SX
  ln_rows32(SH, SX, tid);
  __syncthreads();

  // L2: k,v GEMM 64x64 K=32, 4x4 tile (outputs 32+o*16+og), weights global
  {
    int tg = tid>>4, og = tid&15;
    float acc[4][4];
    #pragma unroll
    for (int o=0;o<4;o++){ float b = in_b[32+o*16+og];
      #pragma unroll
      for (int i=0;i<4;i++) acc[i][o] = b; }
    #pragma unroll 2
    for (int j=0;j<32;j+=4){
      float4 av[4], wv[4];
      #pragma unroll
      for (int i=0;i<4;i++) av[i] = ld4(SX + (tg*4+i)*36 + j);
      #pragma unroll
      for (int o=0;o<4;o++) wv[o] = ld4(in_w + (32+o*16+og)*32 + j);
      #pragma unroll
      for (int i=0;i<4;i++)
        #pragma unroll
        for (int o=0;o<4;o++) acc[i][o] += dot4(av[i], wv[o]);
    }
    #pragma unroll
    for (int i=0;i<4;i++)
      #pragma unroll
      for (int o=0;o<4;o++){
        int ew = 32 + o*16+og, t = tg*4+i;
        if (ew < 64) SY[(ew-32)*68 + t] = acc[i][o];
        else         SY[2176 + (ew-64)*68 + t] = acc[i][o];
      }
  }
  __syncthreads();

  // L3: attention (online softmax). wave=head, lane=query. q weights global.
  float od[8];
  {
    int hh = tid>>6, l = tid&63;
    float qd[8];
    #pragma unroll
    for (int d=0;d<8;d++){
      int e = hh*8+d;
      float a_ = in_b[e];
      #pragma unroll
      for (int k=0;k<8;k++) a_ += dot4(ld4(SX + l*36 + k*4), ld4(in_w + e*32 + k*4));
      qd[d] = a_ * 0.35355339059327373f;
    }
    int njet = s_njet;
    float m = -3.4e38f, lsum = 0.f;
    #pragma unroll
    for (int d=0;d<8;d++) od[d] = 0.f;
    #pragma unroll 1
    for (int s0 = 0; s0 < 64; s0 += 16) {
      float sc[16];
      #pragma unroll
      for (int j=0;j<16;j++) sc[j]=0.f;
      #pragma unroll
      for (int d=0;d<8;d++){
        const float* kr = SY + (hh*8+d)*68 + s0;
        float qv = qd[d];
        #pragma unroll
        for (int j=0;j<16;j+=4){
          float4 kv4 = ld4(kr+j);
          sc[j]  +=qv*kv4.x; sc[j+1]+=qv*kv4.y;
          sc[j+2]+=qv*kv4.z; sc[j+3]+=qv*kv4.w;
        }
      }
      float cm = -3.4e38f;
      #pragma unroll
      for (int j=0;j<16;j++){
        int s = s0+j;
        float a_ = sc[j];
        if (s0 == 0 && l < 9 && j < 9) a_ += b9[j];
        a_ = (s >= njet) ? -1000000000.0f : a_;
        sc[j] = a_;
        cm = fmaxf(cm, a_);
      }
      float nm = fmaxf(m, cm);
      float corr = __expf(m - nm);
      lsum *= corr;
      #pragma unroll
      for (int d=0;d<8;d++) od[d] *= corr;
      #pragma unroll
      for (int j=0;j<16;j++){ sc[j] = __expf(sc[j]-nm); lsum += sc[j]; }
      #pragma unroll
      for (int d=0;d<8;d++){
        const float* vr = SY + 2176 + (hh*8+d)*68 + s0;
        float a_ = 0.f;
        #pragma unroll
        for (int j=0;j<16;j+=4){
          float4 vv = ld4(vr+j);
          a_ += sc[j]*vv.x + sc[j+1]*vv.y + sc[j+2]*vv.z + sc[j+3]*vv.w;
        }
        od[d] += a_;
      }
      m = nm;
    }
    float inv = 1.f/lsum;
    #pragma unroll
    for (int d=0;d<8;d++) od[d] *= inv;
  }
  __syncthreads();
  {
    int hh = tid>>6, l = tid&63;
    st4(&SX[l*36 + hh*8],     make_float4(od[0],od[1],od[2],od[3]));
    st4(&SX[l*36 + hh*8 + 4], make_float4(od[4],od[5],od[6],od[7]));
  }
  __syncthreads();

  // L4: out-proj 64x32 K=32, 4x2 tile -> SY stride 36 (weights global)
  {
    int tg = tid>>4, og = tid&15;
    float acc[4][2];
    #pragma unroll
    for (int o=0;o<2;o++){ float b = out_b[o*16+og];
      #pragma unroll
      for (int i=0;i<4;i++) acc[i][o] = b; }
    #pragma unroll 2
    for (int j=0;j<32;j+=4){
      float4 av[4], wv[2];
      #pragma unroll
      for (int i=0;i<4;i++) av[i] = ld4(SX + (tg*4+i)*36 + j);
      #pragma unroll
      for (int o=0;o<2;o++) wv[o] = ld4(out_w + (o*16+og)*32 + j);
      #pragma unroll
      for (int i=0;i<4;i++)
        #pragma unroll
        for (int o=0;o<2;o++) acc[i][o] += dot4(av[i], wv[o]);
    }
    #pragma unroll
    for (int i=0;i<4;i++)
      #pragma unroll
      for (int o=0;o<2;o++) SY[(tg*4+i)*36 + o*16+og] = acc[i][o];
  }
  __syncthreads();

  // L5: h = ln(y) + h (vectorized)
  {
    int r = tid>>2, g = tid&3;
    const float* row = SY + r*36 + g*8;
    float4 a = ld4(row), b = ld4(row+4);
    float s = a.x+a.y+a.z+a.w + b.x+b.y+b.z+b.w;
    s += __shfl_xor(s,1); s += __shfl_xor(s,2);
    float mean = s * 0.03125f;
    float4 da = make_float4(a.x-mean,a.y-mean,a.z-mean,a.w-mean);
    float4 db = make_float4(b.x-mean,b.y-mean,b.z-mean,b.w-mean);
    float q = dot4(da,da) + dot4(db,db);
    q += __shfl_xor(q,1); q += __shfl_xor(q,2);
    float irs = rsqrtf(q*0.03125f + 1e-5f);
    float* hrow = SH + r*36 + g*8;
    float4 ha = ld4(hrow), hb = ld4(hrow+4);
    st4(hrow,   make_float4(da.x*irs+ha.x, da.y*irs+ha.y, da.z*irs+ha.z, da.w*irs+ha.w));
    st4(hrow+4, make_float4(db.x*irs+hb.x, db.y*irs+hb.y, db.z*irs+hb.z, db.w*irs+hb.w));
  }
  __syncthreads();

  // L6: t = ln(h) -> SX
  ln_rows32(SH, SX, tid);
  __syncthreads();

  // L7: g1 GEMM 64x64 K=32, 4x4 tile -> SY stride 68 + gelu (weights global)
  {
    int tg = tid>>4, og = tid&15;
    float acc[4][4];
    #pragma unroll
    for (int o=0;o<4;o++){ float b = f1b[o*16+og];
      #pragma unroll
      for (int i=0;i<4;i++) acc[i][o] = b; }
    #pragma unroll 2
    for (int j=0;j<32;j+=4){
      float4 av[4], wv[4];
      #pragma unroll
      for (int i=0;i<4;i++) av[i] = ld4(SX + (tg*4+i)*36 + j);
      #pragma unroll
      for (int o=0;o<4;o++) wv[o] = ld4(f1w + (o*16+og)*32 + j);
      #pragma unroll
      for (int i=0;i<4;i++)
        #pragma unroll
        for (int o=0;o<4;o++) acc[i][o] += dot4(av[i], wv[o]);
    }
    #pragma unroll
    for (int i=0;i<4;i++)
      #pragma unroll
      for (int o=0;o<4;o++) SY[(tg*4+i)*68 + o*16+og] = geluf(acc[i][o]);
  }
  __syncthreads();

  // L8: ln64 in-place on SY (vectorized)
  {
    int r = tid>>2, g = tid&3;
    float* row = SY + r*68 + g*16;
    float4 v0 = ld4(row), v1 = ld4(row+4), v2 = ld4(row+8), v3 = ld4(row+12);
    float s = v0.x+v0.y+v0.z+v0.w + v1.x+v1.y+v1.z+v1.w
            + v2.x+v2.y+v2.z+v2.w + v3.x+v3.y+v3.z+v3.w;
    s += __shfl_xor(s,1); s += __shfl_xor(s,2);
    float mean = s * 0.015625f;
    float4 d0 = make_float4(v0.x-mean,v0.y-mean,v0.z-mean,v0.w-mean);
    float4 d1 = make_float4(v1.x-mean,v1.y-mean,v1.z-mean,v1.w-mean);
    float4 d2 = make_float4(v2.x-mean,v2.y-mean,v2.z-mean,v2.w-mean);
    float4 d3 = make_float4(v3.x-mean,v3.y-mean,v3.z-mean,v3.w-mean);
    float q = dot4(d0,d0)+dot4(d1,d1)+dot4(d2,d2)+dot4(d3,d3);
    q += __shfl_xor(q,1); q += __shfl_xor(q,2);
    float irs = rsqrtf(q*0.015625f + 1e-5f);
    st4(row,    make_float4(d0.x*irs,d0.y*irs,d0.z*irs,d0.w*irs));
    st4(row+4,  make_float4(d1.x*irs,d1.y*irs,d1.z*irs,d1.w*irs));
    st4(row+8,  make_float4(d2.x*irs,d2.y*irs,d2.z*irs,d2.w*irs));
    st4(row+12, make_float4(d3.x*irs,d3.y*irs,d3.z*irs,d3.w*irs));
  }
  __syncthreads();

  // L9: g2 GEMM 64x32 K=64, 4x2 tile; h = g2 + wres*h -> G_h (weights global)
  {
    int tg = tid>>4, og = tid&15;
    float acc[4][2];
    #pragma unroll
    for (int o=0;o<2;o++){ float b = f2b[o*16+og];
      #pragma unroll
      for (int i=0;i<4;i++) acc[i][o] = b; }
    #pragma unroll 2
    for (int j=0;j<64;j+=4){
      float4 av[4], wv[2];
      #pragma unroll
      for (int i=0;i<4;i++) av[i] = ld4(SY + (tg*4+i)*68 + j);
      #pragma unroll
      for (int o=0;o<2;o++) wv[o] = ld4(f2w + (o*16+og)*64 + j);
      #pragma unroll
      for (int i=0;i<4;i++)
        #pragma unroll
        for (int o=0;o<2;o++) acc[i][o] += dot4(av[i], wv[o]);
    }
    #pragma unroll
    for (int i=0;i<4;i++)
      #pragma unroll
      for (int o=0;o<2;o++){
        int e = o*16+og, t = tg*4+i;
        G_h[n*2048 + t*32 + e] = acc[i][o] + wres[e]*SH[t*36+e];
      }
  }
}

// ============================ K_cls ========================================
__global__ __launch_bounds__(256, 4) void k_cls(
    const int* __restrict__ ji,
    const float* __restrict__ cb_in_w, const float* __restrict__ cb_in_b,
    const float* __restrict__ cb_out_w, const float* __restrict__ cb_out_b,
    const float* __restrict__ cb_f1_w, const float* __restrict__ cb_f1_b,
    const float* __restrict__ cb_f2_w, const float* __restrict__ cb_f2_b,
    const float* __restrict__ cb_wres, const float* __restrict__ cb_cattn,
    const float* __restrict__ cls_tok, const float* __restrict__ norm_w, const float* __restrict__ norm_b,
    const float* __restrict__ m1w, const float* __restrict__ m1b,
    const float* __restrict__ mhw, const float* __restrict__ mhb,
    const float* __restrict__ mfw, const float* __restrict__ mfb,
    const float* __restrict__ G_h, float* __restrict__ out)
{
  const int n   = blockIdx.x;
  const int tid = threadIdx.x;

  __shared__ __align__(16) float SX[64*36];
  __shared__ __align__(16) float SY[64*68];
  __shared__ __align__(16) float SV[320];
  __shared__ __align__(16) float csh[32];
  __shared__ int s_njet;

  if (tid == 0) s_njet = ji[n*2+1];
  for (int idx = tid; idx < 512; idx += 256) {
    float4 v = ld4(G_h + n*2048 + idx*4);
    int t = idx>>3, e = (idx&7)*4;
    st4(&SX[t*36 + e], v);
  }
  __syncthreads();

  ln_rows32(SX, SX, tid);   // in-place: each lane owns its 8 elements
  if (tid < 32) csh[tid] = cls_tok[tid];
  __syncthreads();

  #pragma unroll 1
  for (int cl = 0; cl < 2; cl++) {
    const float* iw = cb_in_w + cl*3072;
    const float* ib = cb_in_b + cl*96;

    // C1: u0 = ln(csh) -> SV[0..31] (wave 0)
    if (tid < 32) {
      float v = csh[tid];
      float s = v;
      s += __shfl_xor(s,1); s += __shfl_xor(s,2); s += __shfl_xor(s,4); s += __shfl_xor(s,8); s += __shfl_xor(s,16);
      float mean = s * 0.03125f;
      float d = v - mean;
      float q = d*d;
      q += __shfl_xor(q,1); q += __shfl_xor(q,2); q += __shfl_xor(q,4); q += __shfl_xor(q,8); q += __shfl_xor(q,16);
      float irs = rsqrtf(q*0.03125f + 1e-5f);
      SV[tid] = d*irs;
    }
    __syncthreads();

    // C2: q from raw cls (wave 0) -> SV[32..63]
    if (tid < 32) {
      int e = tid;
      float a_ = ib[e];
      #pragma unroll
      for (int k=0;k<8;k++) a_ += dot4(ld4(&csh[k*4]), ld4(iw + e*32 + k*4));
      SV[32+e] = a_ * 0.35355339059327373f;
    }
    // C3a: row 0 (u0) k,v by tid<64
    if (tid < 64) {
      int ew = 32 + tid;
      float a_ = ib[ew];
      #pragma unroll
      for (int k=0;k<8;k++) a_ += dot4(ld4(SV + k*4), ld4(iw + ew*32 + k*4));
      if (ew < 64) SY[(ew-32)*68] = a_;
      else         SY[2176 + (ew-64)*68] = a_;
    }
    // C3b: rows 1..64 (= h rows 0..63), 4x4 register tile, weights global
    {
      int tg = tid>>4, og = tid&15;
      float acc[4][4];
      #pragma unroll
      for (int o=0;o<4;o++){ float b = ib[32+o*16+og];
        #pragma unroll
        for (int i=0;i<4;i++) acc[i][o] = b; }
      #pragma unroll 2
      for (int j=0;j<32;j+=4){
        float4 av[4], wv[4];
        #pragma unroll
        for (int i=0;i<4;i++) av[i] = ld4(SX + (tg*4+i)*36 + j);
        #pragma unroll
        for (int o=0;o<4;o++) wv[o] = ld4(iw + (32+o*16+og)*32 + j);
        #pragma unroll
        for (int i=0;i<4;i++)
          #pragma unroll
          for (int o=0;o<4;o++) acc[i][o] += dot4(av[i], wv[o]);
      }
      #pragma unroll
      for (int i=0;i<4;i++)
        #pragma unroll
        for (int o=0;o<4;o++){
          int ew = 32 + o*16+og, s = tg*4+i + 1;
          if (ew < 64) SY[(ew-32)*68 + s] = acc[i][o];
          else         SY[2176 + (ew-64)*68 + s] = acc[i][o];
        }
    }
    __syncthreads();

    // C4: attention over 65 keys; wave=head, lane=key (lane0 also key 64)
    {
      int hh = tid>>6, l = tid&63;
      int njet = s_njet;
      float q8[8];
      #pragma unroll
      for (int d=0;d<8;d++) q8[d] = SV[32 + hh*8 + d];
      float sc_ = 0.f;
      #pragma unroll
      for (int d=0;d<8;d++) sc_ += q8[d]*SY[(hh*8+d)*68 + l];
      if (l > 0 && (l-1) >= njet) sc_ = -1000000000.0f;
      float sc64 = 0.f;
      if (l == 0){
        #pragma unroll
        for (int d=0;d<8;d++) sc64 += q8[d]*SY[(hh*8+d)*68 + 64];
        if (63 >= njet) sc64 = -1000000000.0f;
      }
      float mx = sc_;
      if (l == 0) mx = fmaxf(mx, sc64);
      mx = fmaxf(mx, __shfl_xor(mx,1));  mx = fmaxf(mx, __shfl_xor(mx,2));
      mx = fmaxf(mx, __shfl_xor(mx,4));  mx = fmaxf(mx, __shfl_xor(mx,8));
      mx = fmaxf(mx, __shfl_xor(mx,16)); mx = fmaxf(mx, __shfl_xor(mx,32));
      float p   = __expf(sc_ - mx);
      float p64 = (l==0) ? __expf(sc64 - mx) : 0.f;
      float ssum = p + p64;
      ssum += __shfl_xor(ssum,1); ssum += __shfl_xor(ssum,2); ssum += __shfl_xor(ssum,4);
      ssum += __shfl_xor(ssum,8); ssum += __shfl_xor(ssum,16); ssum += __shfl_xor(ssum,32);
      float inv = 1.f/ssum;
      #pragma unroll
      for (int d=0;d<8;d++){
        float term = p * SY[2176 + (hh*8+d)*68 + l];
        if (l == 0) term += p64 * SY[2176 + (hh*8+d)*68 + 64];
        term += __shfl_xor(term,1); term += __shfl_xor(term,2); term += __shfl_xor(term,4);
        term += __shfl_xor(term,8); term += __shfl_xor(term,16); term += __shfl_xor(term,32);
        if (l == 0) SV[64 + hh*8 + d] = term*inv;
      }
    }
    __syncthreads();

    // ---- serial chain: wave 0 only, no barriers between sections ----
    if (tid < 32) {
      int e = tid;
      const float* wrow = cb_out_w + (cl*32 + e)*32;
      float a_ = cb_out_b[cl*32 + e];
      #pragma unroll
      for (int j=0;j<32;j++) a_ += SV[64+j]*wrow[j];
      float ca = cb_cattn[cl*4 + (e>>3)];
      SV[96 + (e&7)*4 + (e>>3)] = a_*ca;
    }
    if (tid < 32) {
      float v = SV[96+tid];
      float s = v;
      s += __shfl_xor(s,1); s += __shfl_xor(s,2); s += __shfl_xor(s,4); s += __shfl_xor(s,8); s += __shfl_xor(s,16);
      float mean = s * 0.03125f;
      float d = v - mean;
      float q = d*d;
      q += __shfl_xor(q,1); q += __shfl_xor(q,2); q += __shfl_xor(q,4); q += __shfl_xor(q,8); q += __shfl_xor(q,16);
      float irs = rsqrtf(q*0.03125f + 1e-5f);
      csh[tid] = d*irs + csh[tid];
    }
    if (tid < 32) {
      float v = csh[tid];
      float s = v;
      s += __shfl_xor(s,1); s += __shfl_xor(s,2); s += __shfl_xor(s,4); s += __shfl_xor(s,8); s += __shfl_xor(s,16);
      float mean = s * 0.03125f;
      float d = v - mean;
      float q = d*d;
      q += __shfl_xor(q,1); q += __shfl_xor(q,2); q += __shfl_xor(q,4); q += __shfl_xor(q,8); q += __shfl_xor(q,16);
      float irs = rsqrtf(q*0.03125f + 1e-5f);
      SV[tid] = d*irs;
    }
    if (tid < 64) {
      int o = tid;
      const float* wrow = cb_f1_w + (cl*64+o)*32;
      float a_ = cb_f1_b[cl*64+o];
      #pragma unroll
      for (int j=0;j<32;j++) a_ += SV[j]*wrow[j];
      SV[128+o] = geluf(a_);
    }
    if (tid < 64) {
      float v = SV[128+tid];
      float s = v;
      s += __shfl_xor(s,1); s += __shfl_xor(s,2); s += __shfl_xor(s,4); s += __shfl_xor(s,8);
      s += __shfl_xor(s,16); s += __shfl_xor(s,32);
      float mean = s * 0.015625f;
      float d = v - mean;
      float q = d*d;
      q += __shfl_xor(q,1); q += __shfl_xor(q,2); q += __shfl_xor(q,4); q += __shfl_xor(q,8);
      q += __shfl_xor(q,16); q += __shfl_xor(q,32);
      float irs = rsqrtf(q*0.015625f + 1e-5f);
      SV[192+tid] = d*irs;
    }
    if (tid < 32) {
      int e = tid;
      const float* wrow = cb_f2_w + (cl*32+e)*64;
      float a_ = cb_f2_b[cl*32+e];
      #pragma unroll
      for (int j=0;j<64;j++) a_ += SV[192+j]*wrow[j];
      csh[e] = a_ + cb_wres[cl*32+e]*csh[e];
    }
    __syncthreads();
  }

  // head: wave 0 only
  if (tid < 32) {
    float v = csh[tid];
    float s = v;
    s += __shfl_xor(s,1); s += __shfl_xor(s,2); s += __shfl_xor(s,4); s += __shfl_xor(s,8); s += __shfl_xor(s,16);
    float mean = s * 0.03125f;
    float d = v - mean;
    float q = d*d;
    q += __shfl_xor(q,1); q += __shfl_xor(q,2); q += __shfl_xor(q,4); q += __shfl_xor(q,8); q += __shfl_xor(q,16);
    float irs = rsqrtf(q*0.03125f + 1e-5f);
    SV[tid] = d*irs*norm_w[tid] + norm_b[tid];
  }
  if (tid < 32) {
    float a_ = m1b[tid];
    const float* wrow = m1w + tid*32;
    #pragma unroll
    for (int j=0;j<32;j++) a_ += SV[j]*wrow[j];
    SV[64+tid] = fmaxf(a_, 0.f);
  }
  if (tid < 32) {
    float a_ = mhb[tid];
    const float* wrow = mhw + tid*32;
    #pragma unroll
    for (int j=0;j<32;j++) a_ += SV[64+j]*wrow[j];
    SV[128+tid] = fmaxf(a_, 0.f);
  }
  if (tid == 0) {
    float a_ = mfb[0];
    #pragma unroll
    for (int j=0;j<32;j++) a_ += SV[128+j]*mfw[j];
    out[n] = 1.f/(1.f + expf(-a_));
  }
}

// ---------------------------------------------------------------------------
extern "C" void kernel_launch(void* const* d_in, const int* in_sizes, int n_in,
                              void* d_out, int out_size, void* d_ws, size_t ws_size,
                              hipStream_t stream) {
  (void)in_sizes; (void)n_in; (void)out_size; (void)ws_size;
  const float* x     = (const float*)d_in[0];
  const float* fm    = (const float*)d_in[1];
  const int*   ji    = (const int*)  d_in[2];
  const float* bn_w  = (const float*)d_in[3];
  const float* bn_b  = (const float*)d_in[4];
  const float* e1w   = (const float*)d_in[5];
  const float* e1b   = (const float*)d_in[6];
  const float* e2w   = (const float*)d_in[7];
  const float* e2b   = (const float*)d_in[8];
  const float* c1w   = (const float*)d_in[9];
  const float* c1b   = (const float*)d_in[10];
  const float* c2w   = (const float*)d_in[11];
  const float* c2b   = (const float*)d_in[12];
  const float* pb_in_w  = (const float*)d_in[13];
  const float* pb_in_b  = (const float*)d_in[14];
  const float* pb_out_w = (const float*)d_in[15];
  const float* pb_out_b = (const float*)d_in[16];
  const float* pb_f1_w  = (const float*)d_in[17];
  const float* pb_f1_b  = (const float*)d_in[18];
  const float* pb_f2_w  = (const float*)d_in[19];
  const float* pb_f2_b  = (const float*)d_in[20];
  const float* pb_wres  = (const float*)d_in[21];
  const float* cb_in_w  = (const float*)d_in[22];
  const float* cb_in_b  = (const float*)d_in[23];
  const float* cb_out_w = (const float*)d_in[24];
  const float* cb_out_b = (const float*)d_in[25];
  const float* cb_f1_w  = (const float*)d_in[26];
  const float* cb_f1_b  = (const float*)d_in[27];
  const float* cb_f2_w  = (const float*)d_in[28];
  const float* cb_f2_b  = (const float*)d_in[29];
  const float* cb_wres  = (const float*)d_in[30];
  const float* cb_cattn = (const float*)d_in[31];
  const float* cls_tok  = (const float*)d_in[32];
  const float* norm_w   = (const float*)d_in[33];
  const float* norm_b   = (const float*)d_in[34];
  const float* m1w      = (const float*)d_in[35];
  const float* m1b      = (const float*)d_in[36];
  const float* mhw      = (const float*)d_in[37];
  const float* mhb      = (const float*)d_in[38];
  const float* mfw      = (const float*)d_in[39];
  const float* mfb      = (const float*)d_in[40];

  float* part   = (float*)d_ws;                 // 32768 floats
  float* stats  = part + 32768;                 // 128 floats
  float* G_h    = part + 40960;                 // 2048*2048 floats
  float* G_bias = G_h + 2048*2048;              // 2048*324 floats

  bn_stats_partial<<<256, 256, 0, stream>>>(x, fm, part);
  bn_stats_final<<<1, 64, 0, stream>>>(part, stats);
  k_embed<<<2048, 256, 0, stream>>>(x, fm, stats, bn_w, bn_b, e1w, e1b, e2w, e2b,
                                    c1w, c1b, c2w, c2b, G_h, G_bias);
  for (int li = 0; li < 4; li++) {
    k_layer<<<2048, 256, 0, stream>>>(ji,
        pb_in_w + li*3072, pb_in_b + li*96,
        pb_out_w + li*1024, pb_out_b + li*32,
        pb_f1_w + li*2048, pb_f1_b + li*64,
        pb_f2_w + li*2048, pb_f2_b + li*32,
        pb_wres + li*32, G_h, G_bias);
  }
  k_cls<<<2048, 256, 0, stream>>>(ji, cb_in_w, cb_in_b, cb_out_w, cb_out_b,
                                  cb_f1_w, cb_f1_b, cb_f2_w, cb_f2_b,
                                  cb_wres, cb_cattn, cls_tok, norm_w, norm_b,
                                  m1w, m1b, mhw, mhb, mfw, mfb, G_h, (float*)d_out);
}

// Round 12
// 512.491 us; speedup vs baseline: 1.5221x; 1.5221x over previous
//
#include <hip/hip_runtime.h>

// ---------------------------------------------------------------------------
// Part_65712999629561: ParticleTransformer forward, N=2048, P=64, E=32, H=4,
// D=8. Kernels: stats x2, embed(feat+conv+BN+e1+e2), 4x layer, cls.
// R11 post-mortem: global-weight reads regressed 104->148us (L1/L2 latency >>
// DS pipe). REVERTED to R10 (LDS-staged weights, 537us).
// R12: attention early-exit on fully-masked chunks (s0 >= njet -> break;
// block-uniform, bit-identical math) + maskless fast path for interior
// fully-valid chunks. Mean njet=32 -> ~45% less attention work.
// ---------------------------------------------------------------------------

__device__ __forceinline__ float4 ld4(const float* p){ return *reinterpret_cast<const float4*>(p); }
__device__ __forceinline__ void st4(float* p, float4 v){ *reinterpret_cast<float4*>(p) = v; }
__device__ __forceinline__ float dot4(float4 a, float4 b){ return a.x*b.x + a.y*b.y + a.z*b.z + a.w*b.w; }
__device__ __forceinline__ float geluf(float v){ return 0.5f*v*(1.0f + erff(v*0.70710678118654752f)); }

// ---------------- Kernel A: batchnorm stats --------------------------------
__global__ void bn_stats_partial(const float* __restrict__ x, const float* __restrict__ fm,
                                 float* __restrict__ part) {
  int p  = threadIdx.x & 63;
  int rg = threadIdx.x >> 6;
  float s = 0.f, s2 = 0.f;
  for (int R = blockIdx.x*4 + rg; R < 2048*64; R += 1024) {
    int n_ = R >> 6, c = R & 63;
    float v = (c < 60) ? x[n_*3840 + c*64 + p] : fm[n_*256 + (c-60)*64 + p];
    s += v; s2 += v*v;
  }
  __shared__ float sm[256], sm2[256];
  sm[threadIdx.x] = s; sm2[threadIdx.x] = s2;
  __syncthreads();
  if (threadIdx.x < 64) {
    part[blockIdx.x*128 + p]      = sm[p]+sm[64+p]+sm[128+p]+sm[192+p];
    part[blockIdx.x*128 + 64 + p] = sm2[p]+sm2[64+p]+sm2[128+p]+sm2[192+p];
  }
}

__global__ void bn_stats_final(const float* __restrict__ part, float* __restrict__ stats) {
  int p = threadIdx.x; // 64 threads
  float s = 0.f, s2 = 0.f;
  for (int b = 0; b < 256; b++){ s += part[b*128+p]; s2 += part[b*128+64+p]; }
  float mean = s * (1.f/131072.f);
  float var  = s2 * (1.f/131072.f) - mean*mean;
  stats[p]      = mean;
  stats[64+p]   = rsqrtf(var + 1e-5f);
}

// ---------------- row-LN helpers (vectorized, 64 rows, 4 lanes/row) --------
__device__ __forceinline__ void ln_rows32(const float* src, float* dst, int tid){
  int r = tid>>2, g = tid&3;
  const float* row = src + r*36 + g*8;
  float4 a = ld4(row), b = ld4(row+4);
  float s = a.x+a.y+a.z+a.w + b.x+b.y+b.z+b.w;
  s += __shfl_xor(s,1); s += __shfl_xor(s,2);
  float mean = s * 0.03125f;
  float4 da = make_float4(a.x-mean,a.y-mean,a.z-mean,a.w-mean);
  float4 db = make_float4(b.x-mean,b.y-mean,b.z-mean,b.w-mean);
  float q = dot4(da,da) + dot4(db,db);
  q += __shfl_xor(q,1); q += __shfl_xor(q,2);
  float irs = rsqrtf(q*0.03125f + 1e-5f);
  float* drow = dst + r*36 + g*8;
  st4(drow,   make_float4(da.x*irs, da.y*irs, da.z*irs, da.w*irs));
  st4(drow+4, make_float4(db.x*irs, db.y*irs, db.z*irs, db.w*irs));
}

__device__ __forceinline__ void ln_rows64(const float* src, float* dst, int tid){
  int r = tid>>2, g = tid&3;
  const float* row = src + r*68 + g*16;
  float4 v0 = ld4(row), v1 = ld4(row+4), v2 = ld4(row+8), v3 = ld4(row+12);
  float s = v0.x+v0.y+v0.z+v0.w + v1.x+v1.y+v1.z+v1.w
          + v2.x+v2.y+v2.z+v2.w + v3.x+v3.y+v3.z+v3.w;
  s += __shfl_xor(s,1); s += __shfl_xor(s,2);
  float mean = s * 0.015625f;
  float4 d0 = make_float4(v0.x-mean,v0.y-mean,v0.z-mean,v0.w-mean);
  float4 d1 = make_float4(v1.x-mean,v1.y-mean,v1.z-mean,v1.w-mean);
  float4 d2 = make_float4(v2.x-mean,v2.y-mean,v2.z-mean,v2.w-mean);
  float4 d3 = make_float4(v3.x-mean,v3.y-mean,v3.z-mean,v3.w-mean);
  float q = dot4(d0,d0)+dot4(d1,d1)+dot4(d2,d2)+dot4(d3,d3);
  q += __shfl_xor(q,1); q += __shfl_xor(q,2);
  float irs = rsqrtf(q*0.015625f + 1e-5f);
  float* drow = dst + r*68 + g*16;
  st4(drow,    make_float4(d0.x*irs,d0.y*irs,d0.z*irs,d0.w*irs));
  st4(drow+4,  make_float4(d1.x*irs,d1.y*irs,d1.z*irs,d1.w*irs));
  st4(drow+8,  make_float4(d2.x*irs,d2.y*irs,d2.z*irs,d2.w*irs));
  st4(drow+12, make_float4(d3.x*irs,d3.y*irs,d3.z*irs,d3.w*irs));
}

// ============================ K_embed ======================================
// feat(conv1+conv2 -> G_bias) + BN-apply + ln + e1 + ln + e2 -> G_h.
__global__ __launch_bounds__(256, 3) void k_embed(
    const float* __restrict__ x, const float* __restrict__ fm,
    const float* __restrict__ stats,
    const float* __restrict__ bn_w, const float* __restrict__ bn_b,
    const float* __restrict__ e1w, const float* __restrict__ e1b,
    const float* __restrict__ e2w, const float* __restrict__ e2b,
    const float* __restrict__ c1w_g, const float* __restrict__ c1b_g,
    const float* __restrict__ c2w_g, const float* __restrict__ c2b_g,
    float* __restrict__ G_h, float* __restrict__ G_bias)
{
  const int n   = blockIdx.x;
  const int tid = threadIdx.x;

  __shared__ __align__(16) float SX[64*68];
  __shared__ __align__(16) float SY[64*68];   // scratch: PQ@0[448], C1O@448[1024], CW@1472[328]
  __shared__ __align__(16) float SW[4448];
  __shared__ float SSTAT[128];

  float* PQ  = SY;
  float* C1O = SY + 448;
  float* CW  = SY + 1472;

  if (tid < 64) {
    float mu = stats[tid], rs = stats[64+tid];
    float sc = rs * bn_w[tid];
    SSTAT[tid]      = sc;
    SSTAT[64+tid]   = bn_b[tid] - mu*sc;
  }
  if (tid < 64) {
    int p = tid;
    float e_  = fm[n*256 + p];
    float px_ = fm[n*256 + 64 + p];
    float py_ = fm[n*256 + 128 + p];
    float pz_ = fm[n*256 + 192 + p];
    float pt_ = sqrtf(px_*px_ + py_*py_ + 1e-8f);
    float y_  = 0.5f * logf((e_ + pz_ + 1e-8f) / (e_ - pz_ + 1e-8f));
    float ph_ = atan2f(py_, px_ + 1e-8f);
    if (ph_ < 0.f) ph_ += 6.283185307179586f;
    PQ[0*64+p]=e_; PQ[1*64+p]=px_; PQ[2*64+p]=py_; PQ[3*64+p]=pz_;
    PQ[4*64+p]=pt_; PQ[5*64+p]=y_; PQ[6*64+p]=ph_;
  }
  CW[tid] = c1w_g[tid];
  if (tid < 4)  CW[256+tid] = c1b_g[tid];
  if (tid < 64) CW[260+tid] = c2w_g[tid];
  if (tid < 4)  CW[324+tid] = c2b_g[tid];
  __syncthreads();

  // conv1 (stride4, k4) -> C1O [4][16][16]
  {
    int ho = tid>>4, wo = tid&15;
    float a0=0.f,a1=0.f,a2=0.f,a3=0.f;
    #pragma unroll 1
    for (int kh=0; kh<4; kh++){
      int r = ho*4+kh;
      float er=PQ[r], pxr=PQ[64+r], pyr=PQ[128+r], pzr=PQ[192+r], ptr_=PQ[256+r], yr=PQ[320+r], phr=PQ[384+r];
      #pragma unroll
      for (int kw=0; kw<4; kw++){
        int c = wo*4+kw;
        if (r == c) continue;
        float ec=PQ[c], pxc=PQ[64+c], pyc=PQ[128+c], pzc=PQ[192+c], ptc=PQ[256+c], yc=PQ[320+c], phc=PQ[384+c];
        float dy = yr-yc, dp = phr-phc;
        float delta = sqrtf(fabsf(dy*dy + dp*dp));
        float pmin = fminf(ptr_, ptc);
        float kt = pmin * delta;
        float zz = pmin / (ptr_ + ptc + 1e-8f);
        float sx_ = pxr+pxc, sy_ = pyr+pyc, sz_ = pzr+pzc;
        float m2 = er*er + ec*ec - (sx_*sx_ + sy_*sy_ + sz_*sz_);
        int wb = kh*4+kw;
        a0 += delta*CW[0*64+wb] + kt*CW[0*64+16+wb] + zz*CW[0*64+32+wb] + m2*CW[0*64+48+wb];
        a1 += delta*CW[1*64+wb] + kt*CW[1*64+16+wb] + zz*CW[1*64+32+wb] + m2*CW[1*64+48+wb];
        a2 += delta*CW[2*64+wb] + kt*CW[2*64+16+wb] + zz*CW[2*64+32+wb] + m2*CW[2*64+48+wb];
        a3 += delta*CW[3*64+wb] + kt*CW[3*64+16+wb] + zz*CW[3*64+32+wb] + m2*CW[3*64+48+wb];
      }
    }
    C1O[0*256 + tid] = a0 + CW[256+0];
    C1O[1*256 + tid] = a1 + CW[256+1];
    C1O[2*256 + tid] = a2 + CW[256+2];
    C1O[3*256 + tid] = a3 + CW[256+3];
  }
  __syncthreads();

  // conv2 -> G_bias; BN-apply stage xc -> SX
  for (int idx = tid; idx < 324; idx += 256) {
    int co = idx/81, rem = idx%81, i = rem/9, j = rem%9;
    float s = CW[324+co];
    #pragma unroll
    for (int ci=0; ci<4; ci++){
      #pragma unroll
      for (int kh=0; kh<2; kh++){
        int ri = 2*i - 1 + kh;
        if (ri < 0 || ri >= 16) continue;
        #pragma unroll
        for (int kw=0; kw<2; kw++){
          int cj = 2*j - 1 + kw;
          if (cj < 0 || cj >= 16) continue;
          s += CW[260 + co*16 + ci*4 + kh*2 + kw] * C1O[ci*256 + ri*16 + cj];
        }
      }
    }
    G_bias[n*324 + idx] = s;
  }
  {
    int p4 = (tid & 15) * 4;
    float sc0 = SSTAT[p4], sc1 = SSTAT[p4+1], sc2 = SSTAT[p4+2], sc3 = SSTAT[p4+3];
    float sh0 = SSTAT[64+p4], sh1 = SSTAT[64+p4+1], sh2 = SSTAT[64+p4+2], sh3 = SSTAT[64+p4+3];
    for (int c = tid>>4; c < 64; c += 16) {
      float4 v = (c < 60) ? ld4(x + n*3840 + c*64 + p4) : ld4(fm + n*256 + (c-60)*64 + p4);
      st4(&SX[c*68 + p4], make_float4(v.x*sc0+sh0, v.y*sc1+sh1, v.z*sc2+sh2, v.w*sc3+sh3));
    }
  }
  __syncthreads();

  // ln(xc) -> SY (overwrites conv scratch); stage e1 (64x64 @68) + bias
  ln_rows64(SX, SY, tid);
  for (int idx = tid; idx < 1024; idx += 256) st4(&SW[(idx>>4)*68 + (idx&15)*4], ld4(e1w + idx*4));
  if (tid < 64) SW[4352+tid] = e1b[tid];
  __syncthreads();

  // e1 GEMM 64x64 K=64, 4x4 tile (outputs o*16+og) -> SX (stride 68) + gelu
  {
    int tg = tid>>4, og = tid&15;
    float acc[4][4];
    #pragma unroll
    for (int o=0;o<4;o++){ float b = SW[4352+o*16+og];
      #pragma unroll
      for (int i=0;i<4;i++) acc[i][o] = b; }
    #pragma unroll 2
    for (int j=0;j<64;j+=4){
      float4 av[4], wv[4];
      #pragma unroll
      for (int i=0;i<4;i++) av[i] = ld4(SY + (tg*4+i)*68 + j);
      #pragma unroll
      for (int o=0;o<4;o++) wv[o] = ld4(SW + (o*16+og)*68 + j);
      #pragma unroll
      for (int i=0;i<4;i++)
        #pragma unroll
        for (int o=0;o<4;o++) acc[i][o] += dot4(av[i], wv[o]);
    }
    __syncthreads();
    #pragma unroll
    for (int i=0;i<4;i++)
      #pragma unroll
      for (int o=0;o<4;o++) SX[(tg*4+i)*68 + o*16+og] = geluf(acc[i][o]);
  }
  __syncthreads();

  ln_rows64(SX, SY, tid);
  for (int idx = tid; idx < 512; idx += 256) st4(&SW[(idx>>4)*68 + (idx&15)*4], ld4(e2w + idx*4));
  if (tid < 32) SW[4352+tid] = e2b[tid];
  __syncthreads();

  // e2 GEMM 64x32 K=64, 4x2 tile (outputs o*16+og) -> G_h + gelu
  {
    int tg = tid>>4, og = tid&15;
    float acc[4][2];
    #pragma unroll
    for (int o=0;o<2;o++){ float b = SW[4352+o*16+og];
      #pragma unroll
      for (int i=0;i<4;i++) acc[i][o] = b; }
    #pragma unroll 2
    for (int j=0;j<64;j+=4){
      float4 av[4], wv[2];
      #pragma unroll
      for (int i=0;i<4;i++) av[i] = ld4(SY + (tg*4+i)*68 + j);
      #pragma unroll
      for (int o=0;o<2;o++) wv[o] = ld4(SW + (o*16+og)*68 + j);
      #pragma unroll
      for (int i=0;i<4;i++)
        #pragma unroll
        for (int o=0;o<2;o++) acc[i][o] += dot4(av[i], wv[o]);
    }
    #pragma unroll
    for (int i=0;i<4;i++)
      #pragma unroll
      for (int o=0;o<2;o++) G_h[n*2048 + (tg*4+i)*32 + o*16+og] = geluf(acc[i][o]);
  }
}

// ============================ K_layer ======================================
__global__ __launch_bounds__(256, 3) void k_layer(
    const int* __restrict__ ji,
    const float* __restrict__ in_w,  const float* __restrict__ in_b,
    const float* __restrict__ out_w, const float* __restrict__ out_b,
    const float* __restrict__ f1w,   const float* __restrict__ f1b,
    const float* __restrict__ f2w,   const float* __restrict__ f2b,
    const float* __restrict__ wres,
    float* __restrict__ G_h, const float* __restrict__ G_bias)
{
  const int n   = blockIdx.x;
  const int tid = threadIdx.x;

  __shared__ __align__(16) float SH[64*36];
  __shared__ __align__(16) float SX[64*36];
  __shared__ __align__(16) float SY[64*68];
  __shared__ __align__(16) float SW[3584];
  __shared__ int s_njet;

  if (tid == 0) s_njet = ji[n*2+1];
  float b9[9];
  {
    int hh = tid>>6, l = tid&63;
    if (l < 9) {
      #pragma unroll
      for (int j=0;j<9;j++) b9[j] = G_bias[n*324 + hh*81 + l*9 + j];
    } else {
      #pragma unroll
      for (int j=0;j<9;j++) b9[j] = 0.f;
    }
  }
  for (int idx = tid; idx < 512; idx += 256) {
    float4 v = ld4(G_h + n*2048 + idx*4);
    int t = idx>>3, e = (idx&7)*4;
    st4(&SH[t*36 + e], v);
  }
  __syncthreads();

  // L1: a = ln(h) -> SX; stage in_w (96x32 @36, float4) + in_b
  ln_rows32(SH, SX, tid);
  for (int idx = tid; idx < 768; idx += 256) st4(&SW[(idx>>3)*36 + (idx&7)*4], ld4(in_w + idx*4));
  if (tid < 96) SW[3456+tid] = in_b[tid];
  __syncthreads();

  // L2: k,v GEMM 64x64 K=32, 4x4 tile (outputs 32+o*16+og), transposed -> SY
  {
    int tg = tid>>4, og = tid&15;
    float acc[4][4];
    #pragma unroll
    for (int o=0;o<4;o++){ float b = SW[3456+32+o*16+og];
      #pragma unroll
      for (int i=0;i<4;i++) acc[i][o] = b; }
    #pragma unroll 2
    for (int j=0;j<32;j+=4){
      float4 av[4], wv[4];
      #pragma unroll
      for (int i=0;i<4;i++) av[i] = ld4(SX + (tg*4+i)*36 + j);
      #pragma unroll
      for (int o=0;o<4;o++) wv[o] = ld4(SW + (32+o*16+og)*36 + j);
      #pragma unroll
      for (int i=0;i<4;i++)
        #pragma unroll
        for (int o=0;o<4;o++) acc[i][o] += dot4(av[i], wv[o]);
    }
    #pragma unroll
    for (int i=0;i<4;i++)
      #pragma unroll
      for (int o=0;o<4;o++){
        int ew = 32 + o*16+og, t = tg*4+i;
        if (ew < 64) SY[(ew-32)*68 + t] = acc[i][o];
        else         SY[2176 + (ew-64)*68 + t] = acc[i][o];
      }
  }
  __syncthreads();

  // L3: attention (online softmax, chunked; early-exit on fully-masked chunks)
  float od[8];
  {
    int hh = tid>>6, l = tid&63;
    float qd[8];
    #pragma unroll
    for (int d=0;d<8;d++){
      int e = hh*8+d;
      float a_ = SW[3456+e];
      #pragma unroll
      for (int k=0;k<8;k++) a_ += dot4(ld4(SX + l*36 + k*4), ld4(SW + e*36 + k*4));
      qd[d] = a_ * 0.35355339059327373f;
    }
    int njet = s_njet;
    float m = -3.4e38f, lsum = 0.f;
    #pragma unroll
    for (int d=0;d<8;d++) od[d] = 0.f;
    #pragma unroll 1
    for (int s0 = 0; s0 < 64; s0 += 16) {
      if (s0 >= njet) break;            // fully masked -> contributes nothing
      float sc[16];
      #pragma unroll
      for (int j=0;j<16;j++) sc[j]=0.f;
      #pragma unroll
      for (int d=0;d<8;d++){
        const float* kr = SY + (hh*8+d)*68 + s0;
        float qv = qd[d];
        #pragma unroll
        for (int j=0;j<16;j+=4){
          float4 kv4 = ld4(kr+j);
          sc[j]  +=qv*kv4.x; sc[j+1]+=qv*kv4.y;
          sc[j+2]+=qv*kv4.z; sc[j+3]+=qv*kv4.w;
        }
      }
      float cm = -3.4e38f;
      if (s0 != 0 && s0 + 16 <= njet) {
        // interior fully-valid chunk: no bias, no mask
        #pragma unroll
        for (int j=0;j<16;j++) cm = fmaxf(cm, sc[j]);
      } else {
        #pragma unroll
        for (int j=0;j<16;j++){
          int s = s0+j;
          float a_ = sc[j];
          if (s0 == 0 && l < 9 && j < 9) a_ += b9[j];
          a_ = (s >= njet) ? -1000000000.0f : a_;
          sc[j] = a_;
          cm = fmaxf(cm, a_);
        }
      }
      float nm = fmaxf(m, cm);
      float corr = __expf(m - nm);
      lsum *= corr;
      #pragma unroll
      for (int d=0;d<8;d++) od[d] *= corr;
      #pragma unroll
      for (int j=0;j<16;j++){ sc[j] = __expf(sc[j]-nm); lsum += sc[j]; }
      #pragma unroll
      for (int d=0;d<8;d++){
        const float* vr = SY + 2176 + (hh*8+d)*68 + s0;
        float a_ = 0.f;
        #pragma unroll
        for (int j=0;j<16;j+=4){
          float4 vv = ld4(vr+j);
          a_ += sc[j]*vv.x + sc[j+1]*vv.y + sc[j+2]*vv.z + sc[j+3]*vv.w;
        }
        od[d] += a_;
      }
      m = nm;
    }
    float inv = 1.f/lsum;
    #pragma unroll
    for (int d=0;d<8;d++) od[d] *= inv;
  }
  __syncthreads();
  {
    int hh = tid>>6, l = tid&63;
    st4(&SX[l*36 + hh*8],     make_float4(od[0],od[1],od[2],od[3]));
    st4(&SX[l*36 + hh*8 + 4], make_float4(od[4],od[5],od[6],od[7]));
  }
  for (int idx = tid; idx < 256; idx += 256) st4(&SW[(idx>>3)*36 + (idx&7)*4], ld4(out_w + idx*4));
  if (tid < 32) SW[3456+tid] = out_b[tid];
  __syncthreads();

  // L4: out-proj 64x32 K=32, 4x2 tile (outputs o*16+og) -> SY stride 36
  {
    int tg = tid>>4, og = tid&15;
    float acc[4][2];
    #pragma unroll
    for (int o=0;o<2;o++){ float b = SW[3456+o*16+og];
      #pragma unroll
      for (int i=0;i<4;i++) acc[i][o] = b; }
    #pragma unroll 2
    for (int j=0;j<32;j+=4){
      float4 av[4], wv[2];
      #pragma unroll
      for (int i=0;i<4;i++) av[i] = ld4(SX + (tg*4+i)*36 + j);
      #pragma unroll
      for (int o=0;o<2;o++) wv[o] = ld4(SW + (o*16+og)*36 + j);
      #pragma unroll
      for (int i=0;i<4;i++)
        #pragma unroll
        for (int o=0;o<2;o++) acc[i][o] += dot4(av[i], wv[o]);
    }
    #pragma unroll
    for (int i=0;i<4;i++)
      #pragma unroll
      for (int o=0;o<2;o++) SY[(tg*4+i)*36 + o*16+og] = acc[i][o];
  }
  __syncthreads();

  // L5: h = ln(y) + h (vectorized)
  {
    int r = tid>>2, g = tid&3;
    const float* row = SY + r*36 + g*8;
    float4 a = ld4(row), b = ld4(row+4);
    float s = a.x+a.y+a.z+a.w + b.x+b.y+b.z+b.w;
    s += __shfl_xor(s,1); s += __shfl_xor(s,2);
    float mean = s * 0.03125f;
    float4 da = make_float4(a.x-mean,a.y-mean,a.z-mean,a.w-mean);
    float4 db = make_float4(b.x-mean,b.y-mean,b.z-mean,b.w-mean);
    float q = dot4(da,da) + dot4(db,db);
    q += __shfl_xor(q,1); q += __shfl_xor(q,2);
    float irs = rsqrtf(q*0.03125f + 1e-5f);
    float* hrow = SH + r*36 + g*8;
    float4 ha = ld4(hrow), hb = ld4(hrow+4);
    st4(hrow,   make_float4(da.x*irs+ha.x, da.y*irs+ha.y, da.z*irs+ha.z, da.w*irs+ha.w));
    st4(hrow+4, make_float4(db.x*irs+hb.x, db.y*irs+hb.y, db.z*irs+hb.z, db.w*irs+hb.w));
  }
  __syncthreads();

  // L6: t = ln(h) -> SX; stage f1 (64x32 @36, float4)
  ln_rows32(SH, SX, tid);
  for (int idx = tid; idx < 512; idx += 256) st4(&SW[(idx>>3)*36 + (idx&7)*4], ld4(f1w + idx*4));
  if (tid < 64) SW[3456+tid] = f1b[tid];
  __syncthreads();

  // L7: g1 GEMM 64x64 K=32, 4x4 tile (outputs o*16+og) -> SY stride 68 + gelu
  {
    int tg = tid>>4, og = tid&15;
    float acc[4][4];
    #pragma unroll
    for (int o=0;o<4;o++){ float b = SW[3456+o*16+og];
      #pragma unroll
      for (int i=0;i<4;i++) acc[i][o] = b; }
    #pragma unroll 2
    for (int j=0;j<32;j+=4){
      float4 av[4], wv[4];
      #pragma unroll
      for (int i=0;i<4;i++) av[i] = ld4(SX + (tg*4+i)*36 + j);
      #pragma unroll
      for (int o=0;o<4;o++) wv[o] = ld4(SW + (o*16+og)*36 + j);
      #pragma unroll
      for (int i=0;i<4;i++)
        #pragma unroll
        for (int o=0;o<4;o++) acc[i][o] += dot4(av[i], wv[o]);
    }
    #pragma unroll
    for (int i=0;i<4;i++)
      #pragma unroll
      for (int o=0;o<4;o++) SY[(tg*4+i)*68 + o*16+og] = geluf(acc[i][o]);
  }
  __syncthreads();

  // L8: ln64 in-place on SY; stage f2 (32x64 @68, float4) + bias + wres
  {
    int r = tid>>2, g = tid&3;
    float* row = SY + r*68 + g*16;
    float4 v0 = ld4(row), v1 = ld4(row+4), v2 = ld4(row+8), v3 = ld4(row+12);
    float s = v0.x+v0.y+v0.z+v0.w + v1.x+v1.y+v1.z+v1.w
            + v2.x+v2.y+v2.z+v2.w + v3.x+v3.y+v3.z+v3.w;
    s += __shfl_xor(s,1); s += __shfl_xor(s,2);
    float mean = s * 0.015625f;
    float4 d0 = make_float4(v0.x-mean,v0.y-mean,v0.z-mean,v0.w-mean);
    float4 d1 = make_float4(v1.x-mean,v1.y-mean,v1.z-mean,v1.w-mean);
    float4 d2 = make_float4(v2.x-mean,v2.y-mean,v2.z-mean,v2.w-mean);
    float4 d3 = make_float4(v3.x-mean,v3.y-mean,v3.z-mean,v3.w-mean);
    float q = dot4(d0,d0)+dot4(d1,d1)+dot4(d2,d2)+dot4(d3,d3);
    q += __shfl_xor(q,1); q += __shfl_xor(q,2);
    float irs = rsqrtf(q*0.015625f + 1e-5f);
    st4(row,    make_float4(d0.x*irs,d0.y*irs,d0.z*irs,d0.w*irs));
    st4(row+4,  make_float4(d1.x*irs,d1.y*irs,d1.z*irs,d1.w*irs));
    st4(row+8,  make_float4(d2.x*irs,d2.y*irs,d2.z*irs,d2.w*irs));
    st4(row+12, make_float4(d3.x*irs,d3.y*irs,d3.z*irs,d3.w*irs));
  }
  for (int idx = tid; idx < 512; idx += 256) st4(&SW[(idx>>4)*68 + (idx&15)*4], ld4(f2w + idx*4));
  if (tid < 32){ SW[3456+tid] = f2b[tid]; SW[3488+tid] = wres[tid]; }
  __syncthreads();

  // L9: g2 GEMM 64x32 K=64, 4x2 tile (outputs o*16+og); h = g2 + wres*h -> G_h
  {
    int tg = tid>>4, og = tid&15;
    float acc[4][2];
    #pragma unroll
    for (int o=0;o<2;o++){ float b = SW[3456+o*16+og];
      #pragma unroll
      for (int i=0;i<4;i++) acc[i][o] = b; }
    #pragma unroll 2
    for (int j=0;j<64;j+=4){
      float4 av[4], wv[2];
      #pragma unroll
      for (int i=0;i<4;i++) av[i] = ld4(SY + (tg*4+i)*68 + j);
      #pragma unroll
      for (int o=0;o<2;o++) wv[o] = ld4(SW + (o*16+og)*68 + j);
      #pragma unroll
      for (int i=0;i<4;i++)
        #pragma unroll
        for (int o=0;o<2;o++) acc[i][o] += dot4(av[i], wv[o]);
    }
    #pragma unroll
    for (int i=0;i<4;i++)
      #pragma unroll
      for (int o=0;o<2;o++){
        int e = o*16+og, t = tg*4+i;
        G_h[n*2048 + t*32 + e] = acc[i][o] + SW[3488+e]*SH[t*36+e];
      }
  }
}

// ============================ K_cls ========================================
__global__ __launch_bounds__(256, 3) void k_cls(
    const int* __restrict__ ji,
    const float* __restrict__ cb_in_w, const float* __restrict__ cb_in_b,
    const float* __restrict__ cb_out_w, const float* __restrict__ cb_out_b,
    const float* __restrict__ cb_f1_w, const float* __restrict__ cb_f1_b,
    const float* __restrict__ cb_f2_w, const float* __restrict__ cb_f2_b,
    const float* __restrict__ cb_wres, const float* __restrict__ cb_cattn,
    const float* __restrict__ cls_tok, const float* __restrict__ norm_w, const float* __restrict__ norm_b,
    const float* __restrict__ m1w, const float* __restrict__ m1b,
    const float* __restrict__ mhw, const float* __restrict__ mhb,
    const float* __restrict__ mfw, const float* __restrict__ mfb,
    const float* __restrict__ G_h, float* __restrict__ out)
{
  const int n   = blockIdx.x;
  const int tid = threadIdx.x;

  __shared__ __align__(16) float SX[64*36];
  __shared__ __align__(16) float SY[64*68];
  __shared__ __align__(16) float SW[3584];
  __shared__ __align__(16) float SV[320];
  __shared__ __align__(16) float csh[32];
  __shared__ int s_njet;

  if (tid == 0) s_njet = ji[n*2+1];
  for (int idx = tid; idx < 512; idx += 256) {
    float4 v = ld4(G_h + n*2048 + idx*4);
    int t = idx>>3, e = (idx&7)*4;
    st4(&SX[t*36 + e], v);
  }
  __syncthreads();

  ln_rows32(SX, SX, tid);   // in-place: each lane owns its 8 elements
  if (tid < 32) csh[tid] = cls_tok[tid];
  __syncthreads();

  #pragma unroll 1
  for (int cl = 0; cl < 2; cl++) {
    const float* iw = cb_in_w + cl*3072;
    const float* ib = cb_in_b + cl*96;

    // C1: u0 = ln(csh) -> SV[0..31] (wave 0)
    if (tid < 32) {
      float v = csh[tid];
      float s = v;
      s += __shfl_xor(s,1); s += __shfl_xor(s,2); s += __shfl_xor(s,4); s += __shfl_xor(s,8); s += __shfl_xor(s,16);
      float mean = s * 0.03125f;
      float d = v - mean;
      float q = d*d;
      q += __shfl_xor(q,1); q += __shfl_xor(q,2); q += __shfl_xor(q,4); q += __shfl_xor(q,8); q += __shfl_xor(q,16);
      float irs = rsqrtf(q*0.03125f + 1e-5f);
      SV[tid] = d*irs;
    }
    for (int idx = tid; idx < 768; idx += 256) st4(&SW[(idx>>3)*36 + (idx&7)*4], ld4(iw + idx*4));
    if (tid < 96) SW[3456+tid] = ib[tid];
    __syncthreads();

    // C2: q from raw cls (wave 0) -> SV[32..63]
    if (tid < 32) {
      int e = tid;
      float a_ = SW[3456+e];
      #pragma unroll
      for (int k=0;k<8;k++) a_ += dot4(ld4(&csh[k*4]), ld4(SW + e*36 + k*4));
      SV[32+e] = a_ * 0.35355339059327373f;
    }
    // C3a: row 0 (u0) k,v by tid<64
    if (tid < 64) {
      int ew = 32 + tid;
      float a_ = SW[3456+ew];
      #pragma unroll
      for (int k=0;k<8;k++) a_ += dot4(ld4(SV + k*4), ld4(SW + ew*36 + k*4));
      if (ew < 64) SY[(ew-32)*68] = a_;
      else         SY[2176 + (ew-64)*68] = a_;
    }
    // C3b: rows 1..64 (= h rows 0..63), 4x4 register tile (outputs 32+o*16+og)
    {
      int tg = tid>>4, og = tid&15;
      float acc[4][4];
      #pragma unroll
      for (int o=0;o<4;o++){ float b = SW[3456+32+o*16+og];
        #pragma unroll
        for (int i=0;i<4;i++) acc[i][o] = b; }
      #pragma unroll 2
      for (int j=0;j<32;j+=4){
        float4 av[4], wv[4];
        #pragma unroll
        for (int i=0;i<4;i++) av[i] = ld4(SX + (tg*4+i)*36 + j);
        #pragma unroll
        for (int o=0;o<4;o++) wv[o] = ld4(SW + (32+o*16+og)*36 + j);
        #pragma unroll
        for (int i=0;i<4;i++)
          #pragma unroll
          for (int o=0;o<4;o++) acc[i][o] += dot4(av[i], wv[o]);
      }
      #pragma unroll
      for (int i=0;i<4;i++)
        #pragma unroll
        for (int o=0;o<4;o++){
          int ew = 32 + o*16+og, s = tg*4+i + 1;
          if (ew < 64) SY[(ew-32)*68 + s] = acc[i][o];
          else         SY[2176 + (ew-64)*68 + s] = acc[i][o];
        }
    }
    __syncthreads();

    // C4: attention over 65 keys; wave=head, lane=key (lane0 also key 64)
    {
      int hh = tid>>6, l = tid&63;
      int njet = s_njet;
      float q8[8];
      #pragma unroll
      for (int d=0;d<8;d++) q8[d] = SV[32 + hh*8 + d];
      float sc_ = 0.f;
      #pragma unroll
      for (int d=0;d<8;d++) sc_ += q8[d]*SY[(hh*8+d)*68 + l];
      if (l > 0 && (l-1) >= njet) sc_ = -1000000000.0f;
      float sc64 = 0.f;
      if (l == 0){
        #pragma unroll
        for (int d=0;d<8;d++) sc64 += q8[d]*SY[(hh*8+d)*68 + 64];
        if (63 >= njet) sc64 = -1000000000.0f;
      }
      float mx = sc_;
      if (l == 0) mx = fmaxf(mx, sc64);
      mx = fmaxf(mx, __shfl_xor(mx,1));  mx = fmaxf(mx, __shfl_xor(mx,2));
      mx = fmaxf(mx, __shfl_xor(mx,4));  mx = fmaxf(mx, __shfl_xor(mx,8));
      mx = fmaxf(mx, __shfl_xor(mx,16)); mx = fmaxf(mx, __shfl_xor(mx,32));
      float p   = __expf(sc_ - mx);
      float p64 = (l==0) ? __expf(sc64 - mx) : 0.f;
      float ssum = p + p64;
      ssum += __shfl_xor(ssum,1); ssum += __shfl_xor(ssum,2); ssum += __shfl_xor(ssum,4);
      ssum += __shfl_xor(ssum,8); ssum += __shfl_xor(ssum,16); ssum += __shfl_xor(ssum,32);
      float inv = 1.f/ssum;
      #pragma unroll
      for (int d=0;d<8;d++){
        float term = p * SY[2176 + (hh*8+d)*68 + l];
        if (l == 0) term += p64 * SY[2176 + (hh*8+d)*68 + 64];
        term += __shfl_xor(term,1); term += __shfl_xor(term,2); term += __shfl_xor(term,4);
        term += __shfl_xor(term,8); term += __shfl_xor(term,16); term += __shfl_xor(term,32);
        if (l == 0) SV[64 + hh*8 + d] = term*inv;
      }
    }
    __syncthreads();

    // ---- serial chain: wave 0 only, no barriers between sections ----
    if (tid < 32) {
      int e = tid;
      const float* wrow = cb_out_w + (cl*32 + e)*32;
      float a_ = cb_out_b[cl*32 + e];
      #pragma unroll
      for (int j=0;j<32;j++) a_ += SV[64+j]*wrow[j];
      float ca = cb_cattn[cl*4 + (e>>3)];
      SV[96 + (e&7)*4 + (e>>3)] = a_*ca;
    }
    if (tid < 32) {
      float v = SV[96+tid];
      float s = v;
      s += __shfl_xor(s,1); s += __shfl_xor(s,2); s += __shfl_xor(s,4); s += __shfl_xor(s,8); s += __shfl_xor(s,16);
      float mean = s * 0.03125f;
      float d = v - mean;
      float q = d*d;
      q += __shfl_xor(q,1); q += __shfl_xor(q,2); q += __shfl_xor(q,4); q += __shfl_xor(q,8); q += __shfl_xor(q,16);
      float irs = rsqrtf(q*0.03125f + 1e-5f);
      csh[tid] = d*irs + csh[tid];
    }
    if (tid < 32) {
      float v = csh[tid];
      float s = v;
      s += __shfl_xor(s,1); s += __shfl_xor(s,2); s += __shfl_xor(s,4); s += __shfl_xor(s,8); s += __shfl_xor(s,16);
      float mean = s * 0.03125f;
      float d = v - mean;
      float q = d*d;
      q += __shfl_xor(q,1); q += __shfl_xor(q,2); q += __shfl_xor(q,4); q += __shfl_xor(q,8); q += __shfl_xor(q,16);
      float irs = rsqrtf(q*0.03125f + 1e-5f);
      SV[tid] = d*irs;
    }
    if (tid < 64) {
      int o = tid;
      const float* wrow = cb_f1_w + (cl*64+o)*32;
      float a_ = cb_f1_b[cl*64+o];
      #pragma unroll
      for (int j=0;j<32;j++) a_ += SV[j]*wrow[j];
      SV[128+o] = geluf(a_);
    }
    if (tid < 64) {
      float v = SV[128+tid];
      float s = v;
      s += __shfl_xor(s,1); s += __shfl_xor(s,2); s += __shfl_xor(s,4); s += __shfl_xor(s,8);
      s += __shfl_xor(s,16); s += __shfl_xor(s,32);
      float mean = s * 0.015625f;
      float d = v - mean;
      float q = d*d;
      q += __shfl_xor(q,1); q += __shfl_xor(q,2); q += __shfl_xor(q,4); q += __shfl_xor(q,8);
      q += __shfl_xor(q,16); q += __shfl_xor(q,32);
      float irs = rsqrtf(q*0.015625f + 1e-5f);
      SV[192+tid] = d*irs;
    }
    if (tid < 32) {
      int e = tid;
      const float* wrow = cb_f2_w + (cl*32+e)*64;
      float a_ = cb_f2_b[cl*32+e];
      #pragma unroll
      for (int j=0;j<64;j++) a_ += SV[192+j]*wrow[j];
      csh[e] = a_ + cb_wres[cl*32+e]*csh[e];
    }
    // next iteration's staging barrier provides cross-wave sync
  }

  // head: wave 0 only
  if (tid < 32) {
    float v = csh[tid];
    float s = v;
    s += __shfl_xor(s,1); s += __shfl_xor(s,2); s += __shfl_xor(s,4); s += __shfl_xor(s,8); s += __shfl_xor(s,16);
    float mean = s * 0.03125f;
    float d = v - mean;
    float q = d*d;
    q += __shfl_xor(q,1); q += __shfl_xor(q,2); q += __shfl_xor(q,4); q += __shfl_xor(q,8); q += __shfl_xor(q,16);
    float irs = rsqrtf(q*0.03125f + 1e-5f);
    SV[tid] = d*irs*norm_w[tid] + norm_b[tid];
  }
  if (tid < 32) {
    float a_ = m1b[tid];
    const float* wrow = m1w + tid*32;
    #pragma unroll
    for (int j=0;j<32;j++) a_ += SV[j]*wrow[j];
    SV[64+tid] = fmaxf(a_, 0.f);
  }
  if (tid < 32) {
    float a_ = mhb[tid];
    const float* wrow = mhw + tid*32;
    #pragma unroll
    for (int j=0;j<32;j++) a_ += SV[64+j]*wrow[j];
    SV[128+tid] = fmaxf(a_, 0.f);
  }
  if (tid == 0) {
    float a_ = mfb[0];
    #pragma unroll
    for (int j=0;j<32;j++) a_ += SV[128+j]*mfw[j];
    out[n] = 1.f/(1.f + expf(-a_));
  }
}

// ---------------------------------------------------------------------------
extern "C" void kernel_launch(void* const* d_in, const int* in_sizes, int n_in,
                              void* d_out, int out_size, void* d_ws, size_t ws_size,
                              hipStream_t stream) {
  (void)in_sizes; (void)n_in; (void)out_size; (void)ws_size;
  const float* x     = (const float*)d_in[0];
  const float* fm    = (const float*)d_in[1];
  const int*   ji    = (const int*)  d_in[2];
  const float* bn_w  = (const float*)d_in[3];
  const float* bn_b  = (const float*)d_in[4];
  const float* e1w   = (const float*)d_in[5];
  const float* e1b   = (const float*)d_in[6];
  const float* e2w   = (const float*)d_in[7];
  const float* e2b   = (const float*)d_in[8];
  const float* c1w   = (const float*)d_in[9];
  const float* c1b   = (const float*)d_in[10];
  const float* c2w   = (const float*)d_in[11];
  const float* c2b   = (const float*)d_in[12];
  const float* pb_in_w  = (const float*)d_in[13];
  const float* pb_in_b  = (const float*)d_in[14];
  const float* pb_out_w = (const float*)d_in[15];
  const float* pb_out_b = (const float*)d_in[16];
  const float* pb_f1_w  = (const float*)d_in[17];
  const float* pb_f1_b  = (const float*)d_in[18];
  const float* pb_f2_w  = (const float*)d_in[19];
  const float* pb_f2_b  = (const float*)d_in[20];
  const float* pb_wres  = (const float*)d_in[21];
  const float* cb_in_w  = (const float*)d_in[22];
  const float* cb_in_b  = (const float*)d_in[23];
  const float* cb_out_w = (const float*)d_in[24];
  const float* cb_out_b = (const float*)d_in[25];
  const float* cb_f1_w  = (const float*)d_in[26];
  const float* cb_f1_b  = (const float*)d_in[27];
  const float* cb_f2_w  = (const float*)d_in[28];
  const float* cb_f2_b  = (const float*)d_in[29];
  const float* cb_wres  = (const float*)d_in[30];
  const float* cb_cattn = (const float*)d_in[31];
  const float* cls_tok  = (const float*)d_in[32];
  const float* norm_w   = (const float*)d_in[33];
  const float* norm_b   = (const float*)d_in[34];
  const float* m1w      = (const float*)d_in[35];
  const float* m1b      = (const float*)d_in[36];
  const float* mhw      = (const float*)d_in[37];
  const float* mhb      = (const float*)d_in[38];
  const float* mfw      = (const float*)d_in[39];
  const float* mfb      = (const float*)d_in[40];

  float* part   = (float*)d_ws;                 // 32768 floats
  float* stats  = part + 32768;                 // 128 floats
  float* G_h    = part + 40960;                 // 2048*2048 floats
  float* G_bias = G_h + 2048*2048;              // 2048*324 floats

  bn_stats_partial<<<256, 256, 0, stream>>>(x, fm, part);
  bn_stats_final<<<1, 64, 0, stream>>>(part, stats);
  k_embed<<<2048, 256, 0, stream>>>(x, fm, stats, bn_w, bn_b, e1w, e1b, e2w, e2b,
                                    c1w, c1b, c2w, c2b, G_h, G_bias);
  for (int li = 0; li < 4; li++) {
    k_layer<<<2048, 256, 0, stream>>>(ji,
        pb_in_w + li*3072, pb_in_b + li*96,
        pb_out_w + li*1024, pb_out_b + li*32,
        pb_f1_w + li*2048, pb_f1_b + li*64,
        pb_f2_w + li*2048, pb_f2_b + li*32,
        pb_wres + li*32, G_h, G_bias);
  }
  k_cls<<<2048, 256, 0, stream>>>(ji, cb_in_w, cb_in_b, cb_out_w, cb_out_b,
                                  cb_f1_w, cb_f1_b, cb_f2_w, cb_f2_b,
                                  cb_wres, cb_cattn, cls_tok, norm_w, norm_b,
                                  m1w, m1b, mhw, mhb, mfw, mfb, G_h, (float*)d_out);
}

// Round 13
// 498.541 us; speedup vs baseline: 1.5646x; 1.0280x over previous
//
#include <hip/hip_runtime.h>

// ---------------------------------------------------------------------------
// Part_65712999629561: ParticleTransformer forward, N=2048, P=64, E=32, H=4,
// D=8. Kernels: stats x2, embed(feat+conv+BN+e1+e2), 4x layer, cls.
// R12: 512us (attn chunk early-exit). R13: DEAD-ROW SKIP — token rows >= njet
// are masked as keys in every attention (incl. cls) and feed nothing else, so
// all row-parallel phases skip wave-uniformly (wave w owns rows 16w..16w+15).
// k_cls C3b zero-fills skipped k/v (C4 shfl-sum would propagate 0*NaN);
// k_layer needs no fill (masked chunks never read). Mean active = 62.5%.
// ---------------------------------------------------------------------------

__device__ __forceinline__ float4 ld4(const float* p){ return *reinterpret_cast<const float4*>(p); }
__device__ __forceinline__ void st4(float* p, float4 v){ *reinterpret_cast<float4*>(p) = v; }
__device__ __forceinline__ float dot4(float4 a, float4 b){ return a.x*b.x + a.y*b.y + a.z*b.z + a.w*b.w; }
__device__ __forceinline__ float geluf(float v){ return 0.5f*v*(1.0f + erff(v*0.70710678118654752f)); }

// ---------------- Kernel A: batchnorm stats --------------------------------
__global__ void bn_stats_partial(const float* __restrict__ x, const float* __restrict__ fm,
                                 float* __restrict__ part) {
  int p  = threadIdx.x & 63;
  int rg = threadIdx.x >> 6;
  float s = 0.f, s2 = 0.f;
  for (int R = blockIdx.x*4 + rg; R < 2048*64; R += 1024) {
    int n_ = R >> 6, c = R & 63;
    float v = (c < 60) ? x[n_*3840 + c*64 + p] : fm[n_*256 + (c-60)*64 + p];
    s += v; s2 += v*v;
  }
  __shared__ float sm[256], sm2[256];
  sm[threadIdx.x] = s; sm2[threadIdx.x] = s2;
  __syncthreads();
  if (threadIdx.x < 64) {
    part[blockIdx.x*128 + p]      = sm[p]+sm[64+p]+sm[128+p]+sm[192+p];
    part[blockIdx.x*128 + 64 + p] = sm2[p]+sm2[64+p]+sm2[128+p]+sm2[192+p];
  }
}

__global__ void bn_stats_final(const float* __restrict__ part, float* __restrict__ stats) {
  int p = threadIdx.x; // 64 threads
  float s = 0.f, s2 = 0.f;
  for (int b = 0; b < 256; b++){ s += part[b*128+p]; s2 += part[b*128+64+p]; }
  float mean = s * (1.f/131072.f);
  float var  = s2 * (1.f/131072.f) - mean*mean;
  stats[p]      = mean;
  stats[64+p]   = rsqrtf(var + 1e-5f);
}

// ---------------- row-LN helpers (vectorized, 64 rows, 4 lanes/row) --------
__device__ __forceinline__ void ln_rows32(const float* src, float* dst, int tid){
  int r = tid>>2, g = tid&3;
  const float* row = src + r*36 + g*8;
  float4 a = ld4(row), b = ld4(row+4);
  float s = a.x+a.y+a.z+a.w + b.x+b.y+b.z+b.w;
  s += __shfl_xor(s,1); s += __shfl_xor(s,2);
  float mean = s * 0.03125f;
  float4 da = make_float4(a.x-mean,a.y-mean,a.z-mean,a.w-mean);
  float4 db = make_float4(b.x-mean,b.y-mean,b.z-mean,b.w-mean);
  float q = dot4(da,da) + dot4(db,db);
  q += __shfl_xor(q,1); q += __shfl_xor(q,2);
  float irs = rsqrtf(q*0.03125f + 1e-5f);
  float* drow = dst + r*36 + g*8;
  st4(drow,   make_float4(da.x*irs, da.y*irs, da.z*irs, da.w*irs));
  st4(drow+4, make_float4(db.x*irs, db.y*irs, db.z*irs, db.w*irs));
}

__device__ __forceinline__ void ln_rows64(const float* src, float* dst, int tid){
  int r = tid>>2, g = tid&3;
  const float* row = src + r*68 + g*16;
  float4 v0 = ld4(row), v1 = ld4(row+4), v2 = ld4(row+8), v3 = ld4(row+12);
  float s = v0.x+v0.y+v0.z+v0.w + v1.x+v1.y+v1.z+v1.w
          + v2.x+v2.y+v2.z+v2.w + v3.x+v3.y+v3.z+v3.w;
  s += __shfl_xor(s,1); s += __shfl_xor(s,2);
  float mean = s * 0.015625f;
  float4 d0 = make_float4(v0.x-mean,v0.y-mean,v0.z-mean,v0.w-mean);
  float4 d1 = make_float4(v1.x-mean,v1.y-mean,v1.z-mean,v1.w-mean);
  float4 d2 = make_float4(v2.x-mean,v2.y-mean,v2.z-mean,v2.w-mean);
  float4 d3 = make_float4(v3.x-mean,v3.y-mean,v3.z-mean,v3.w-mean);
  float q = dot4(d0,d0)+dot4(d1,d1)+dot4(d2,d2)+dot4(d3,d3);
  q += __shfl_xor(q,1); q += __shfl_xor(q,2);
  float irs = rsqrtf(q*0.015625f + 1e-5f);
  float* drow = dst + r*68 + g*16;
  st4(drow,    make_float4(d0.x*irs,d0.y*irs,d0.z*irs,d0.w*irs));
  st4(drow+4,  make_float4(d1.x*irs,d1.y*irs,d1.z*irs,d1.w*irs));
  st4(drow+8,  make_float4(d2.x*irs,d2.y*irs,d2.z*irs,d2.w*irs));
  st4(drow+12, make_float4(d3.x*irs,d3.y*irs,d3.z*irs,d3.w*irs));
}

// ============================ K_embed ======================================
__global__ __launch_bounds__(256, 3) void k_embed(
    const float* __restrict__ x, const float* __restrict__ fm,
    const int* __restrict__ ji,
    const float* __restrict__ stats,
    const float* __restrict__ bn_w, const float* __restrict__ bn_b,
    const float* __restrict__ e1w, const float* __restrict__ e1b,
    const float* __restrict__ e2w, const float* __restrict__ e2b,
    const float* __restrict__ c1w_g, const float* __restrict__ c1b_g,
    const float* __restrict__ c2w_g, const float* __restrict__ c2b_g,
    float* __restrict__ G_h, float* __restrict__ G_bias)
{
  const int n   = blockIdx.x;
  const int tid = threadIdx.x;
  const int njet = ji[n*2+1];
  const bool wact = ((tid>>6)<<4) < njet;   // wave owns rows 16w..16w+15

  __shared__ __align__(16) float SX[64*68];
  __shared__ __align__(16) float SY[64*68];   // scratch: PQ@0, C1O@448, CW@1472
  __shared__ __align__(16) float SW[4448];
  __shared__ float SSTAT[128];

  float* PQ  = SY;
  float* C1O = SY + 448;
  float* CW  = SY + 1472;

  if (tid < 64) {
    float mu = stats[tid], rs = stats[64+tid];
    float sc = rs * bn_w[tid];
    SSTAT[tid]      = sc;
    SSTAT[64+tid]   = bn_b[tid] - mu*sc;
  }
  if (tid < 64) {
    int p = tid;
    float e_  = fm[n*256 + p];
    float px_ = fm[n*256 + 64 + p];
    float py_ = fm[n*256 + 128 + p];
    float pz_ = fm[n*256 + 192 + p];
    float pt_ = sqrtf(px_*px_ + py_*py_ + 1e-8f);
    float y_  = 0.5f * logf((e_ + pz_ + 1e-8f) / (e_ - pz_ + 1e-8f));
    float ph_ = atan2f(py_, px_ + 1e-8f);
    if (ph_ < 0.f) ph_ += 6.283185307179586f;
    PQ[0*64+p]=e_; PQ[1*64+p]=px_; PQ[2*64+p]=py_; PQ[3*64+p]=pz_;
    PQ[4*64+p]=pt_; PQ[5*64+p]=y_; PQ[6*64+p]=ph_;
  }
  CW[tid] = c1w_g[tid];
  if (tid < 4)  CW[256+tid] = c1b_g[tid];
  if (tid < 64) CW[260+tid] = c2w_g[tid];
  if (tid < 4)  CW[324+tid] = c2b_g[tid];
  __syncthreads();

  // conv1 (stride4, k4) -> C1O [4][16][16]  (needs all 64 particles)
  {
    int ho = tid>>4, wo = tid&15;
    float a0=0.f,a1=0.f,a2=0.f,a3=0.f;
    #pragma unroll 1
    for (int kh=0; kh<4; kh++){
      int r = ho*4+kh;
      float er=PQ[r], pxr=PQ[64+r], pyr=PQ[128+r], pzr=PQ[192+r], ptr_=PQ[256+r], yr=PQ[320+r], phr=PQ[384+r];
      #pragma unroll
      for (int kw=0; kw<4; kw++){
        int c = wo*4+kw;
        if (r == c) continue;
        float ec=PQ[c], pxc=PQ[64+c], pyc=PQ[128+c], pzc=PQ[192+c], ptc=PQ[256+c], yc=PQ[320+c], phc=PQ[384+c];
        float dy = yr-yc, dp = phr-phc;
        float delta = sqrtf(fabsf(dy*dy + dp*dp));
        float pmin = fminf(ptr_, ptc);
        float kt = pmin * delta;
        float zz = pmin / (ptr_ + ptc + 1e-8f);
        float sx_ = pxr+pxc, sy_ = pyr+pyc, sz_ = pzr+pzc;
        float m2 = er*er + ec*ec - (sx_*sx_ + sy_*sy_ + sz_*sz_);
        int wb = kh*4+kw;
        a0 += delta*CW[0*64+wb] + kt*CW[0*64+16+wb] + zz*CW[0*64+32+wb] + m2*CW[0*64+48+wb];
        a1 += delta*CW[1*64+wb] + kt*CW[1*64+16+wb] + zz*CW[1*64+32+wb] + m2*CW[1*64+48+wb];
        a2 += delta*CW[2*64+wb] + kt*CW[2*64+16+wb] + zz*CW[2*64+32+wb] + m2*CW[2*64+48+wb];
        a3 += delta*CW[3*64+wb] + kt*CW[3*64+16+wb] + zz*CW[3*64+32+wb] + m2*CW[3*64+48+wb];
      }
    }
    C1O[0*256 + tid] = a0 + CW[256+0];
    C1O[1*256 + tid] = a1 + CW[256+1];
    C1O[2*256 + tid] = a2 + CW[256+2];
    C1O[3*256 + tid] = a3 + CW[256+3];
  }
  __syncthreads();

  // conv2 -> G_bias; BN-apply stage xc -> SX
  for (int idx = tid; idx < 324; idx += 256) {
    int co = idx/81, rem = idx%81, i = rem/9, j = rem%9;
    float s = CW[324+co];
    #pragma unroll
    for (int ci=0; ci<4; ci++){
      #pragma unroll
      for (int kh=0; kh<2; kh++){
        int ri = 2*i - 1 + kh;
        if (ri < 0 || ri >= 16) continue;
        #pragma unroll
        for (int kw=0; kw<2; kw++){
          int cj = 2*j - 1 + kw;
          if (cj < 0 || cj >= 16) continue;
          s += CW[260 + co*16 + ci*4 + kh*2 + kw] * C1O[ci*256 + ri*16 + cj];
        }
      }
    }
    G_bias[n*324 + idx] = s;
  }
  {
    int p4 = (tid & 15) * 4;
    float sc0 = SSTAT[p4], sc1 = SSTAT[p4+1], sc2 = SSTAT[p4+2], sc3 = SSTAT[p4+3];
    float sh0 = SSTAT[64+p4], sh1 = SSTAT[64+p4+1], sh2 = SSTAT[64+p4+2], sh3 = SSTAT[64+p4+3];
    for (int c = tid>>4; c < 64; c += 16) {
      float4 v = (c < 60) ? ld4(x + n*3840 + c*64 + p4) : ld4(fm + n*256 + (c-60)*64 + p4);
      st4(&SX[c*68 + p4], make_float4(v.x*sc0+sh0, v.y*sc1+sh1, v.z*sc2+sh2, v.w*sc3+sh3));
    }
  }
  __syncthreads();

  // ln(xc) -> SY (rows >= njet dead); stage e1 + bias
  if (wact) ln_rows64(SX, SY, tid);
  for (int idx = tid; idx < 1024; idx += 256) st4(&SW[(idx>>4)*68 + (idx&15)*4], ld4(e1w + idx*4));
  if (tid < 64) SW[4352+tid] = e1b[tid];
  __syncthreads();

  // e1 GEMM 64x64 K=64 (row-skip) -> SX + gelu
  {
    int tg = tid>>4, og = tid&15;
    float acc[4][4];
    #pragma unroll
    for (int o=0;o<4;o++){ float b = SW[4352+o*16+og];
      #pragma unroll
      for (int i=0;i<4;i++) acc[i][o] = b; }
    if (wact) {
      #pragma unroll 2
      for (int j=0;j<64;j+=4){
        float4 av[4], wv[4];
        #pragma unroll
        for (int i=0;i<4;i++) av[i] = ld4(SY + (tg*4+i)*68 + j);
        #pragma unroll
        for (int o=0;o<4;o++) wv[o] = ld4(SW + (o*16+og)*68 + j);
        #pragma unroll
        for (int i=0;i<4;i++)
          #pragma unroll
          for (int o=0;o<4;o++) acc[i][o] += dot4(av[i], wv[o]);
      }
    }
    __syncthreads();
    if (wact) {
      #pragma unroll
      for (int i=0;i<4;i++)
        #pragma unroll
        for (int o=0;o<4;o++) SX[(tg*4+i)*68 + o*16+og] = geluf(acc[i][o]);
    }
  }
  __syncthreads();

  if (wact) ln_rows64(SX, SY, tid);
  for (int idx = tid; idx < 512; idx += 256) st4(&SW[(idx>>4)*68 + (idx&15)*4], ld4(e2w + idx*4));
  if (tid < 32) SW[4352+tid] = e2b[tid];
  __syncthreads();

  // e2 GEMM 64x32 K=64 (row-skip) -> G_h + gelu
  if (wact) {
    int tg = tid>>4, og = tid&15;
    float acc[4][2];
    #pragma unroll
    for (int o=0;o<2;o++){ float b = SW[4352+o*16+og];
      #pragma unroll
      for (int i=0;i<4;i++) acc[i][o] = b; }
    #pragma unroll 2
    for (int j=0;j<64;j+=4){
      float4 av[4], wv[2];
      #pragma unroll
      for (int i=0;i<4;i++) av[i] = ld4(SY + (tg*4+i)*68 + j);
      #pragma unroll
      for (int o=0;o<2;o++) wv[o] = ld4(SW + (o*16+og)*68 + j);
      #pragma unroll
      for (int i=0;i<4;i++)
        #pragma unroll
        for (int o=0;o<2;o++) acc[i][o] += dot4(av[i], wv[o]);
    }
    #pragma unroll
    for (int i=0;i<4;i++)
      #pragma unroll
      for (int o=0;o<2;o++) G_h[n*2048 + (tg*4+i)*32 + o*16+og] = geluf(acc[i][o]);
  }
}

// ============================ K_layer ======================================
__global__ __launch_bounds__(256, 3) void k_layer(
    const int* __restrict__ ji,
    const float* __restrict__ in_w,  const float* __restrict__ in_b,
    const float* __restrict__ out_w, const float* __restrict__ out_b,
    const float* __restrict__ f1w,   const float* __restrict__ f1b,
    const float* __restrict__ f2w,   const float* __restrict__ f2b,
    const float* __restrict__ wres,
    float* __restrict__ G_h, const float* __restrict__ G_bias)
{
  const int n   = blockIdx.x;
  const int tid = threadIdx.x;
  const int njet = ji[n*2+1];
  const int nt16 = (njet + 15) & ~15;
  const bool wact = ((tid>>6)<<4) < njet;

  __shared__ __align__(16) float SH[64*36];
  __shared__ __align__(16) float SX[64*36];
  __shared__ __align__(16) float SY[64*68];
  __shared__ __align__(16) float SW[3584];

  float b9[9];
  {
    int hh = tid>>6, l = tid&63;
    if (l < 9) {
      #pragma unroll
      for (int j=0;j<9;j++) b9[j] = G_bias[n*324 + hh*81 + l*9 + j];
    } else {
      #pragma unroll
      for (int j=0;j<9;j++) b9[j] = 0.f;
    }
  }
  for (int idx = tid; idx < (nt16<<3); idx += 256) {
    float4 v = ld4(G_h + n*2048 + idx*4);
    int t = idx>>3, e = (idx&7)*4;
    st4(&SH[t*36 + e], v);
  }
  __syncthreads();

  // L1: a = ln(h) -> SX (row-skip); stage in_w + in_b
  if (wact) ln_rows32(SH, SX, tid);
  for (int idx = tid; idx < 768; idx += 256) st4(&SW[(idx>>3)*36 + (idx&7)*4], ld4(in_w + idx*4));
  if (tid < 96) SW[3456+tid] = in_b[tid];
  __syncthreads();

  // L2: k,v GEMM (row-skip; masked chunks never read -> no zero-fill)
  if (wact) {
    int tg = tid>>4, og = tid&15;
    float acc[4][4];
    #pragma unroll
    for (int o=0;o<4;o++){ float b = SW[3456+32+o*16+og];
      #pragma unroll
      for (int i=0;i<4;i++) acc[i][o] = b; }
    #pragma unroll 2
    for (int j=0;j<32;j+=4){
      float4 av[4], wv[4];
      #pragma unroll
      for (int i=0;i<4;i++) av[i] = ld4(SX + (tg*4+i)*36 + j);
      #pragma unroll
      for (int o=0;o<4;o++) wv[o] = ld4(SW + (32+o*16+og)*36 + j);
      #pragma unroll
      for (int i=0;i<4;i++)
        #pragma unroll
        for (int o=0;o<4;o++) acc[i][o] += dot4(av[i], wv[o]);
    }
    #pragma unroll
    for (int i=0;i<4;i++)
      #pragma unroll
      for (int o=0;o<4;o++){
        int ew = 32 + o*16+og, t = tg*4+i;
        if (ew < 64) SY[(ew-32)*68 + t] = acc[i][o];
        else         SY[2176 + (ew-64)*68 + t] = acc[i][o];
      }
  }
  __syncthreads();

  // L3: attention (online softmax; chunks only up to njet)
  float od[8];
  {
    int hh = tid>>6, l = tid&63;
    float qd[8];
    #pragma unroll
    for (int d=0;d<8;d++){
      int e = hh*8+d;
      float a_ = SW[3456+e];
      #pragma unroll
      for (int k=0;k<8;k++) a_ += dot4(ld4(SX + l*36 + k*4), ld4(SW + e*36 + k*4));
      qd[d] = a_ * 0.35355339059327373f;
    }
    float m = -3.4e38f, lsum = 0.f;
    #pragma unroll
    for (int d=0;d<8;d++) od[d] = 0.f;
    #pragma unroll 1
    for (int s0 = 0; s0 < njet; s0 += 16) {
      float sc[16];
      #pragma unroll
      for (int j=0;j<16;j++) sc[j]=0.f;
      #pragma unroll
      for (int d=0;d<8;d++){
        const float* kr = SY + (hh*8+d)*68 + s0;
        float qv = qd[d];
        #pragma unroll
        for (int j=0;j<16;j+=4){
          float4 kv4 = ld4(kr+j);
          sc[j]  +=qv*kv4.x; sc[j+1]+=qv*kv4.y;
          sc[j+2]+=qv*kv4.z; sc[j+3]+=qv*kv4.w;
        }
      }
      float cm = -3.4e38f;
      if (s0 != 0 && s0 + 16 <= njet) {
        #pragma unroll
        for (int j=0;j<16;j++) cm = fmaxf(cm, sc[j]);
      } else {
        #pragma unroll
        for (int j=0;j<16;j++){
          int s = s0+j;
          float a_ = sc[j];
          if (s0 == 0 && l < 9 && j < 9) a_ += b9[j];
          a_ = (s >= njet) ? -1000000000.0f : a_;
          sc[j] = a_;
          cm = fmaxf(cm, a_);
        }
      }
      float nm = fmaxf(m, cm);
      float corr = __expf(m - nm);
      lsum *= corr;
      #pragma unroll
      for (int d=0;d<8;d++) od[d] *= corr;
      #pragma unroll
      for (int j=0;j<16;j++){ sc[j] = __expf(sc[j]-nm); lsum += sc[j]; }
      #pragma unroll
      for (int d=0;d<8;d++){
        const float* vr = SY + 2176 + (hh*8+d)*68 + s0;
        float a_ = 0.f;
        #pragma unroll
        for (int j=0;j<16;j+=4){
          float4 vv = ld4(vr+j);
          a_ += sc[j]*vv.x + sc[j+1]*vv.y + sc[j+2]*vv.z + sc[j+3]*vv.w;
        }
        od[d] += a_;
      }
      m = nm;
    }
    float inv = 1.f/lsum;
    #pragma unroll
    for (int d=0;d<8;d++) od[d] *= inv;
  }
  __syncthreads();
  {
    int hh = tid>>6, l = tid&63;
    st4(&SX[l*36 + hh*8],     make_float4(od[0],od[1],od[2],od[3]));
    st4(&SX[l*36 + hh*8 + 4], make_float4(od[4],od[5],od[6],od[7]));
  }
  for (int idx = tid; idx < 256; idx += 256) st4(&SW[(idx>>3)*36 + (idx&7)*4], ld4(out_w + idx*4));
  if (tid < 32) SW[3456+tid] = out_b[tid];
  __syncthreads();

  // L4: out-proj (row-skip) -> SY stride 36
  if (wact) {
    int tg = tid>>4, og = tid&15;
    float acc[4][2];
    #pragma unroll
    for (int o=0;o<2;o++){ float b = SW[3456+o*16+og];
      #pragma unroll
      for (int i=0;i<4;i++) acc[i][o] = b; }
    #pragma unroll 2
    for (int j=0;j<32;j+=4){
      float4 av[4], wv[2];
      #pragma unroll
      for (int i=0;i<4;i++) av[i] = ld4(SX + (tg*4+i)*36 + j);
      #pragma unroll
      for (int o=0;o<2;o++) wv[o] = ld4(SW + (o*16+og)*36 + j);
      #pragma unroll
      for (int i=0;i<4;i++)
        #pragma unroll
        for (int o=0;o<2;o++) acc[i][o] += dot4(av[i], wv[o]);
    }
    #pragma unroll
    for (int i=0;i<4;i++)
      #pragma unroll
      for (int o=0;o<2;o++) SY[(tg*4+i)*36 + o*16+og] = acc[i][o];
  }
  __syncthreads();

  // L5: h = ln(y) + h (row-skip)
  if (wact) {
    int r = tid>>2, g = tid&3;
    const float* row = SY + r*36 + g*8;
    float4 a = ld4(row), b = ld4(row+4);
    float s = a.x+a.y+a.z+a.w + b.x+b.y+b.z+b.w;
    s += __shfl_xor(s,1); s += __shfl_xor(s,2);
    float mean = s * 0.03125f;
    float4 da = make_float4(a.x-mean,a.y-mean,a.z-mean,a.w-mean);
    float4 db = make_float4(b.x-mean,b.y-mean,b.z-mean,b.w-mean);
    float q = dot4(da,da) + dot4(db,db);
    q += __shfl_xor(q,1); q += __shfl_xor(q,2);
    float irs = rsqrtf(q*0.03125f + 1e-5f);
    float* hrow = SH + r*36 + g*8;
    float4 ha = ld4(hrow), hb = ld4(hrow+4);
    st4(hrow,   make_float4(da.x*irs+ha.x, da.y*irs+ha.y, da.z*irs+ha.z, da.w*irs+ha.w));
    st4(hrow+4, make_float4(db.x*irs+hb.x, db.y*irs+hb.y, db.z*irs+hb.z, db.w*irs+hb.w));
  }
  __syncthreads();

  // L6: t = ln(h) -> SX (row-skip); stage f1
  if (wact) ln_rows32(SH, SX, tid);
  for (int idx = tid; idx < 512; idx += 256) st4(&SW[(idx>>3)*36 + (idx&7)*4], ld4(f1w + idx*4));
  if (tid < 64) SW[3456+tid] = f1b[tid];
  __syncthreads();

  // L7: g1 GEMM (row-skip) -> SY stride 68 + gelu
  if (wact) {
    int tg = tid>>4, og = tid&15;
    float acc[4][4];
    #pragma unroll
    for (int o=0;o<4;o++){ float b = SW[3456+o*16+og];
      #pragma unroll
      for (int i=0;i<4;i++) acc[i][o] = b; }
    #pragma unroll 2
    for (int j=0;j<32;j+=4){
      float4 av[4], wv[4];
      #pragma unroll
      for (int i=0;i<4;i++) av[i] = ld4(SX + (tg*4+i)*36 + j);
      #pragma unroll
      for (int o=0;o<4;o++) wv[o] = ld4(SW + (o*16+og)*36 + j);
      #pragma unroll
      for (int i=0;i<4;i++)
        #pragma unroll
        for (int o=0;o<4;o++) acc[i][o] += dot4(av[i], wv[o]);
    }
    #pragma unroll
    for (int i=0;i<4;i++)
      #pragma unroll
      for (int o=0;o<4;o++) SY[(tg*4+i)*68 + o*16+og] = geluf(acc[i][o]);
  }
  __syncthreads();

  // L8: ln64 in-place on SY (row-skip); stage f2 + bias + wres
  if (wact) {
    int r = tid>>2, g = tid&3;
    float* row = SY + r*68 + g*16;
    float4 v0 = ld4(row), v1 = ld4(row+4), v2 = ld4(row+8), v3 = ld4(row+12);
    float s = v0.x+v0.y+v0.z+v0.w + v1.x+v1.y+v1.z+v1.w
            + v2.x+v2.y+v2.z+v2.w + v3.x+v3.y+v3.z+v3.w;
    s += __shfl_xor(s,1); s += __shfl_xor(s,2);
    float mean = s * 0.015625f;
    float4 d0 = make_float4(v0.x-mean,v0.y-mean,v0.z-mean,v0.w-mean);
    float4 d1 = make_float4(v1.x-mean,v1.y-mean,v1.z-mean,v1.w-mean);
    float4 d2 = make_float4(v2.x-mean,v2.y-mean,v2.z-mean,v2.w-mean);
    float4 d3 = make_float4(v3.x-mean,v3.y-mean,v3.z-mean,v3.w-mean);
    float q = dot4(d0,d0)+dot4(d1,d1)+dot4(d2,d2)+dot4(d3,d3);
    q += __shfl_xor(q,1); q += __shfl_xor(q,2);
    float irs = rsqrtf(q*0.015625f + 1e-5f);
    st4(row,    make_float4(d0.x*irs,d0.y*irs,d0.z*irs,d0.w*irs));
    st4(row+4,  make_float4(d1.x*irs,d1.y*irs,d1.z*irs,d1.w*irs));
    st4(row+8,  make_float4(d2.x*irs,d2.y*irs,d2.z*irs,d2.w*irs));
    st4(row+12, make_float4(d3.x*irs,d3.y*irs,d3.z*irs,d3.w*irs));
  }
  for (int idx = tid; idx < 512; idx += 256) st4(&SW[(idx>>4)*68 + (idx&15)*4], ld4(f2w + idx*4));
  if (tid < 32){ SW[3456+tid] = f2b[tid]; SW[3488+tid] = wres[tid]; }
  __syncthreads();

  // L9: g2 GEMM (row-skip); h = g2 + wres*h -> G_h
  if (wact) {
    int tg = tid>>4, og = tid&15;
    float acc[4][2];
    #pragma unroll
    for (int o=0;o<2;o++){ float b = SW[3456+o*16+og];
      #pragma unroll
      for (int i=0;i<4;i++) acc[i][o] = b; }
    #pragma unroll 2
    for (int j=0;j<64;j+=4){
      float4 av[4], wv[2];
      #pragma unroll
      for (int i=0;i<4;i++) av[i] = ld4(SY + (tg*4+i)*68 + j);
      #pragma unroll
      for (int o=0;o<2;o++) wv[o] = ld4(SW + (o*16+og)*68 + j);
      #pragma unroll
      for (int i=0;i<4;i++)
        #pragma unroll
        for (int o=0;o<2;o++) acc[i][o] += dot4(av[i], wv[o]);
    }
    #pragma unroll
    for (int i=0;i<4;i++)
      #pragma unroll
      for (int o=0;o<2;o++){
        int e = o*16+og, t = tg*4+i;
        G_h[n*2048 + t*32 + e] = acc[i][o] + SW[3488+e]*SH[t*36+e];
      }
  }
}

// ============================ K_cls ========================================
__global__ __launch_bounds__(256, 3) void k_cls(
    const int* __restrict__ ji,
    const float* __restrict__ cb_in_w, const float* __restrict__ cb_in_b,
    const float* __restrict__ cb_out_w, const float* __restrict__ cb_out_b,
    const float* __restrict__ cb_f1_w, const float* __restrict__ cb_f1_b,
    const float* __restrict__ cb_f2_w, const float* __restrict__ cb_f2_b,
    const float* __restrict__ cb_wres, const float* __restrict__ cb_cattn,
    const float* __restrict__ cls_tok, const float* __restrict__ norm_w, const float* __restrict__ norm_b,
    const float* __restrict__ m1w, const float* __restrict__ m1b,
    const float* __restrict__ mhw, const float* __restrict__ mhb,
    const float* __restrict__ mfw, const float* __restrict__ mfb,
    const float* __restrict__ G_h, float* __restrict__ out)
{
  const int n   = blockIdx.x;
  const int tid = threadIdx.x;
  const int njet = ji[n*2+1];
  const int nt16 = (njet + 15) & ~15;
  const bool wact = ((tid>>6)<<4) < njet;

  __shared__ __align__(16) float SX[64*36];
  __shared__ __align__(16) float SY[64*68];
  __shared__ __align__(16) float SW[3584];
  __shared__ __align__(16) float SV[320];
  __shared__ __align__(16) float csh[32];

  for (int idx = tid; idx < (nt16<<3); idx += 256) {
    float4 v = ld4(G_h + n*2048 + idx*4);
    int t = idx>>3, e = (idx&7)*4;
    st4(&SX[t*36 + e], v);
  }
  __syncthreads();

  if (wact) ln_rows32(SX, SX, tid);   // in-place, row-skip
  if (tid < 32) csh[tid] = cls_tok[tid];
  __syncthreads();

  #pragma unroll 1
  for (int cl = 0; cl < 2; cl++) {
    const float* iw = cb_in_w + cl*3072;
    const float* ib = cb_in_b + cl*96;

    // C1: u0 = ln(csh) -> SV[0..31] (wave 0)
    if (tid < 32) {
      float v = csh[tid];
      float s = v;
      s += __shfl_xor(s,1); s += __shfl_xor(s,2); s += __shfl_xor(s,4); s += __shfl_xor(s,8); s += __shfl_xor(s,16);
      float mean = s * 0.03125f;
      float d = v - mean;
      float q = d*d;
      q += __shfl_xor(q,1); q += __shfl_xor(q,2); q += __shfl_xor(q,4); q += __shfl_xor(q,8); q += __shfl_xor(q,16);
      float irs = rsqrtf(q*0.03125f + 1e-5f);
      SV[tid] = d*irs;
    }
    for (int idx = tid; idx < 768; idx += 256) st4(&SW[(idx>>3)*36 + (idx&7)*4], ld4(iw + idx*4));
    if (tid < 96) SW[3456+tid] = ib[tid];
    __syncthreads();

    // C2: q from raw cls (wave 0) -> SV[32..63]
    if (tid < 32) {
      int e = tid;
      float a_ = SW[3456+e];
      #pragma unroll
      for (int k=0;k<8;k++) a_ += dot4(ld4(&csh[k*4]), ld4(SW + e*36 + k*4));
      SV[32+e] = a_ * 0.35355339059327373f;
    }
    // C3a: row 0 (u0) k,v by tid<64
    if (tid < 64) {
      int ew = 32 + tid;
      float a_ = SW[3456+ew];
      #pragma unroll
      for (int k=0;k<8;k++) a_ += dot4(ld4(SV + k*4), ld4(SW + ew*36 + k*4));
      if (ew < 64) SY[(ew-32)*68] = a_;
      else         SY[2176 + (ew-64)*68] = a_;
    }
    // C3b: rows 1..64, 4x4 tile; skipped waves ZERO-FILL (C4 shfl-sums 0*v)
    {
      int tg = tid>>4, og = tid&15;
      if (wact) {
        float acc[4][4];
        #pragma unroll
        for (int o=0;o<4;o++){ float b = SW[3456+32+o*16+og];
          #pragma unroll
          for (int i=0;i<4;i++) acc[i][o] = b; }
        #pragma unroll 2
        for (int j=0;j<32;j+=4){
          float4 av[4], wv[4];
          #pragma unroll
          for (int i=0;i<4;i++) av[i] = ld4(SX + (tg*4+i)*36 + j);
          #pragma unroll
          for (int o=0;o<4;o++) wv[o] = ld4(SW + (32+o*16+og)*36 + j);
          #pragma unroll
          for (int i=0;i<4;i++)
            #pragma unroll
            for (int o=0;o<4;o++) acc[i][o] += dot4(av[i], wv[o]);
        }
        #pragma unroll
        for (int i=0;i<4;i++)
          #pragma unroll
          for (int o=0;o<4;o++){
            int ew = 32 + o*16+og, s = tg*4+i + 1;
            if (ew < 64) SY[(ew-32)*68 + s] = acc[i][o];
            else         SY[2176 + (ew-64)*68 + s] = acc[i][o];
          }
      } else {
        #pragma unroll
        for (int i=0;i<4;i++)
          #pragma unroll
          for (int o=0;o<4;o++){
            int ew = 32 + o*16+og, s = tg*4+i + 1;
            if (ew < 64) SY[(ew-32)*68 + s] = 0.f;
            else         SY[2176 + (ew-64)*68 + s] = 0.f;
          }
      }
    }
    __syncthreads();

    // C4: attention over 65 keys; wave=head, lane=key (lane0 also key 64)
    {
      int hh = tid>>6, l = tid&63;
      float q8[8];
      #pragma unroll
      for (int d=0;d<8;d++) q8[d] = SV[32 + hh*8 + d];
      float sc_ = 0.f;
      #pragma unroll
      for (int d=0;d<8;d++) sc_ += q8[d]*SY[(hh*8+d)*68 + l];
      if (l > 0 && (l-1) >= njet) sc_ = -1000000000.0f;
      float sc64 = 0.f;
      if (l == 0){
        #pragma unroll
        for (int d=0;d<8;d++) sc64 += q8[d]*SY[(hh*8+d)*68 + 64];
        if (63 >= njet) sc64 = -1000000000.0f;
      }
      float mx = sc_;
      if (l == 0) mx = fmaxf(mx, sc64);
      mx = fmaxf(mx, __shfl_xor(mx,1));  mx = fmaxf(mx, __shfl_xor(mx,2));
      mx = fmaxf(mx, __shfl_xor(mx,4));  mx = fmaxf(mx, __shfl_xor(mx,8));
      mx = fmaxf(mx, __shfl_xor(mx,16)); mx = fmaxf(mx, __shfl_xor(mx,32));
      float p   = __expf(sc_ - mx);
      float p64 = (l==0) ? __expf(sc64 - mx) : 0.f;
      float ssum = p + p64;
      ssum += __shfl_xor(ssum,1); ssum += __shfl_xor(ssum,2); ssum += __shfl_xor(ssum,4);
      ssum += __shfl_xor(ssum,8); ssum += __shfl_xor(ssum,16); ssum += __shfl_xor(ssum,32);
      float inv = 1.f/ssum;
      #pragma unroll
      for (int d=0;d<8;d++){
        float term = p * SY[2176 + (hh*8+d)*68 + l];
        if (l == 0) term += p64 * SY[2176 + (hh*8+d)*68 + 64];
        term += __shfl_xor(term,1); term += __shfl_xor(term,2); term += __shfl_xor(term,4);
        term += __shfl_xor(term,8); term += __shfl_xor(term,16); term += __shfl_xor(term,32);
        if (l == 0) SV[64 + hh*8 + d] = term*inv;
      }
    }
    __syncthreads();

    // ---- serial chain: wave 0 only ----
    if (tid < 32) {
      int e = tid;
      const float* wrow = cb_out_w + (cl*32 + e)*32;
      float a_ = cb_out_b[cl*32 + e];
      #pragma unroll
      for (int j=0;j<32;j++) a_ += SV[64+j]*wrow[j];
      float ca = cb_cattn[cl*4 + (e>>3)];
      SV[96 + (e&7)*4 + (e>>3)] = a_*ca;
    }
    if (tid < 32) {
      float v = SV[96+tid];
      float s = v;
      s += __shfl_xor(s,1); s += __shfl_xor(s,2); s += __shfl_xor(s,4); s += __shfl_xor(s,8); s += __shfl_xor(s,16);
      float mean = s * 0.03125f;
      float d = v - mean;
      float q = d*d;
      q += __shfl_xor(q,1); q += __shfl_xor(q,2); q += __shfl_xor(q,4); q += __shfl_xor(q,8); q += __shfl_xor(q,16);
      float irs = rsqrtf(q*0.03125f + 1e-5f);
      csh[tid] = d*irs + csh[tid];
    }
    if (tid < 32) {
      float v = csh[tid];
      float s = v;
      s += __shfl_xor(s,1); s += __shfl_xor(s,2); s += __shfl_xor(s,4); s += __shfl_xor(s,8); s += __shfl_xor(s,16);
      float mean = s * 0.03125f;
      float d = v - mean;
      float q = d*d;
      q += __shfl_xor(q,1); q += __shfl_xor(q,2); q += __shfl_xor(q,4); q += __shfl_xor(q,8); q += __shfl_xor(q,16);
      float irs = rsqrtf(q*0.03125f + 1e-5f);
      SV[tid] = d*irs;
    }
    if (tid < 64) {
      int o = tid;
      const float* wrow = cb_f1_w + (cl*64+o)*32;
      float a_ = cb_f1_b[cl*64+o];
      #pragma unroll
      for (int j=0;j<32;j++) a_ += SV[j]*wrow[j];
      SV[128+o] = geluf(a_);
    }
    if (tid < 64) {
      float v = SV[128+tid];
      float s = v;
      s += __shfl_xor(s,1); s += __shfl_xor(s,2); s += __shfl_xor(s,4); s += __shfl_xor(s,8);
      s += __shfl_xor(s,16); s += __shfl_xor(s,32);
      float mean = s * 0.015625f;
      float d = v - mean;
      float q = d*d;
      q += __shfl_xor(q,1); q += __shfl_xor(q,2); q += __shfl_xor(q,4); q += __shfl_xor(q,8);
      q += __shfl_xor(q,16); q += __shfl_xor(q,32);
      float irs = rsqrtf(q*0.015625f + 1e-5f);
      SV[192+tid] = d*irs;
    }
    if (tid < 32) {
      int e = tid;
      const float* wrow = cb_f2_w + (cl*32+e)*64;
      float a_ = cb_f2_b[cl*32+e];
      #pragma unroll
      for (int j=0;j<64;j++) a_ += SV[192+j]*wrow[j];
      csh[e] = a_ + cb_wres[cl*32+e]*csh[e];
    }
    // next iteration's staging barrier provides cross-wave sync
  }

  // head: wave 0 only
  if (tid < 32) {
    float v = csh[tid];
    float s = v;
    s += __shfl_xor(s,1); s += __shfl_xor(s,2); s += __shfl_xor(s,4); s += __shfl_xor(s,8); s += __shfl_xor(s,16);
    float mean = s * 0.03125f;
    float d = v - mean;
    float q = d*d;
    q += __shfl_xor(q,1); q += __shfl_xor(q,2); q += __shfl_xor(q,4); q += __shfl_xor(q,8); q += __shfl_xor(q,16);
    float irs = rsqrtf(q*0.03125f + 1e-5f);
    SV[tid] = d*irs*norm_w[tid] + norm_b[tid];
  }
  if (tid < 32) {
    float a_ = m1b[tid];
    const float* wrow = m1w + tid*32;
    #pragma unroll
    for (int j=0;j<32;j++) a_ += SV[j]*wrow[j];
    SV[64+tid] = fmaxf(a_, 0.f);
  }
  if (tid < 32) {
    float a_ = mhb[tid];
    const float* wrow = mhw + tid*32;
    #pragma unroll
    for (int j=0;j<32;j++) a_ += SV[64+j]*wrow[j];
    SV[128+tid] = fmaxf(a_, 0.f);
  }
  if (tid == 0) {
    float a_ = mfb[0];
    #pragma unroll
    for (int j=0;j<32;j++) a_ += SV[128+j]*mfw[j];
    out[n] = 1.f/(1.f + expf(-a_));
  }
}

// ---------------------------------------------------------------------------
extern "C" void kernel_launch(void* const* d_in, const int* in_sizes, int n_in,
                              void* d_out, int out_size, void* d_ws, size_t ws_size,
                              hipStream_t stream) {
  (void)in_sizes; (void)n_in; (void)out_size; (void)ws_size;
  const float* x     = (const float*)d_in[0];
  const float* fm    = (const float*)d_in[1];
  const int*   ji    = (const int*)  d_in[2];
  const float* bn_w  = (const float*)d_in[3];
  const float* bn_b  = (const float*)d_in[4];
  const float* e1w   = (const float*)d_in[5];
  const float* e1b   = (const float*)d_in[6];
  const float* e2w   = (const float*)d_in[7];
  const float* e2b   = (const float*)d_in[8];
  const float* c1w   = (const float*)d_in[9];
  const float* c1b   = (const float*)d_in[10];
  const float* c2w   = (const float*)d_in[11];
  const float* c2b   = (const float*)d_in[12];
  const float* pb_in_w  = (const float*)d_in[13];
  const float* pb_in_b  = (const float*)d_in[14];
  const float* pb_out_w = (const float*)d_in[15];
  const float* pb_out_b = (const float*)d_in[16];
  const float* pb_f1_w  = (const float*)d_in[17];
  const float* pb_f1_b  = (const float*)d_in[18];
  const float* pb_f2_w  = (const float*)d_in[19];
  const float* pb_f2_b  = (const float*)d_in[20];
  const float* pb_wres  = (const float*)d_in[21];
  const float* cb_in_w  = (const float*)d_in[22];
  const float* cb_in_b  = (const float*)d_in[23];
  const float* cb_out_w = (const float*)d_in[24];
  const float* cb_out_b = (const float*)d_in[25];
  const float* cb_f1_w  = (const float*)d_in[26];
  const float* cb_f1_b  = (const float*)d_in[27];
  const float* cb_f2_w  = (const float*)d_in[28];
  const float* cb_f2_b  = (const float*)d_in[29];
  const float* cb_wres  = (const float*)d_in[30];
  const float* cb_cattn = (const float*)d_in[31];
  const float* cls_tok  = (const float*)d_in[32];
  const float* norm_w   = (const float*)d_in[33];
  const float* norm_b   = (const float*)d_in[34];
  const float* m1w      = (const float*)d_in[35];
  const float* m1b      = (const float*)d_in[36];
  const float* mhw      = (const float*)d_in[37];
  const float* mhb      = (const float*)d_in[38];
  const float* mfw      = (const float*)d_in[39];
  const float* mfb      = (const float*)d_in[40];

  float* part   = (float*)d_ws;                 // 32768 floats
  float* stats  = part + 32768;                 // 128 floats
  float* G_h    = part + 40960;                 // 2048*2048 floats
  float* G_bias = G_h + 2048*2048;              // 2048*324 floats

  bn_stats_partial<<<256, 256, 0, stream>>>(x, fm, part);
  bn_stats_final<<<1, 64, 0, stream>>>(part, stats);
  k_embed<<<2048, 256, 0, stream>>>(x, fm, ji, stats, bn_w, bn_b, e1w, e1b, e2w, e2b,
                                    c1w, c1b, c2w, c2b, G_h, G_bias);
  for (int li = 0; li < 4; li++) {
    k_layer<<<2048, 256, 0, stream>>>(ji,
        pb_in_w + li*3072, pb_in_b + li*96,
        pb_out_w + li*1024, pb_out_b + li*32,
        pb_f1_w + li*2048, pb_f1_b + li*64,
        pb_f2_w + li*2048, pb_f2_b + li*32,
        pb_wres + li*32, G_h, G_bias);
  }
  k_cls<<<2048, 256, 0, stream>>>(ji, cb_in_w, cb_in_b, cb_out_w, cb_out_b,
                                  cb_f1_w, cb_f1_b, cb_f2_w, cb_f2_b,
                                  cb_wres, cb_cattn, cls_tok, norm_w, norm_b,
                                  m1w, m1b, mhw, mhb, mfw, mfb, G_h, (float*)d_out);
}

// Round 14
// 479.992 us; speedup vs baseline: 1.6251x; 1.0386x over previous
//
#include <hip/hip_runtime.h>

// ---------------------------------------------------------------------------
// Part_65712999629561: ParticleTransformer forward. R13: 498us (dead-row skip).
// R14: k_layer holds h in REGISTERS (ln mapping: thread(r=tid>>2,g=tid&3) owns
// 8 elems) -> SH deleted -> LDS 50176->40960 B -> 4 blocks/CU
// (launch_bounds(256,4)); L5+L6 fused (one barrier saved); L9 writes raw g2,
// final reg pass applies wres residual + G_h store.
// ---------------------------------------------------------------------------

__device__ __forceinline__ float4 ld4(const float* p){ return *reinterpret_cast<const float4*>(p); }
__device__ __forceinline__ void st4(float* p, float4 v){ *reinterpret_cast<float4*>(p) = v; }
__device__ __forceinline__ float dot4(float4 a, float4 b){ return a.x*b.x + a.y*b.y + a.z*b.z + a.w*b.w; }
__device__ __forceinline__ float geluf(float v){ return 0.5f*v*(1.0f + erff(v*0.70710678118654752f)); }

// ---------------- Kernel A: batchnorm stats --------------------------------
__global__ void bn_stats_partial(const float* __restrict__ x, const float* __restrict__ fm,
                                 float* __restrict__ part) {
  int p  = threadIdx.x & 63;
  int rg = threadIdx.x >> 6;
  float s = 0.f, s2 = 0.f;
  for (int R = blockIdx.x*4 + rg; R < 2048*64; R += 1024) {
    int n_ = R >> 6, c = R & 63;
    float v = (c < 60) ? x[n_*3840 + c*64 + p] : fm[n_*256 + (c-60)*64 + p];
    s += v; s2 += v*v;
  }
  __shared__ float sm[256], sm2[256];
  sm[threadIdx.x] = s; sm2[threadIdx.x] = s2;
  __syncthreads();
  if (threadIdx.x < 64) {
    part[blockIdx.x*128 + p]      = sm[p]+sm[64+p]+sm[128+p]+sm[192+p];
    part[blockIdx.x*128 + 64 + p] = sm2[p]+sm2[64+p]+sm2[128+p]+sm2[192+p];
  }
}

__global__ void bn_stats_final(const float* __restrict__ part, float* __restrict__ stats) {
  int p = threadIdx.x; // 64 threads
  float s = 0.f, s2 = 0.f;
  for (int b = 0; b < 256; b++){ s += part[b*128+p]; s2 += part[b*128+64+p]; }
  float mean = s * (1.f/131072.f);
  float var  = s2 * (1.f/131072.f) - mean*mean;
  stats[p]      = mean;
  stats[64+p]   = rsqrtf(var + 1e-5f);
}

// ---------------- row-LN helpers (vectorized, 64 rows, 4 lanes/row) --------
__device__ __forceinline__ void ln_rows32(const float* src, float* dst, int tid){
  int r = tid>>2, g = tid&3;
  const float* row = src + r*36 + g*8;
  float4 a = ld4(row), b = ld4(row+4);
  float s = a.x+a.y+a.z+a.w + b.x+b.y+b.z+b.w;
  s += __shfl_xor(s,1); s += __shfl_xor(s,2);
  float mean = s * 0.03125f;
  float4 da = make_float4(a.x-mean,a.y-mean,a.z-mean,a.w-mean);
  float4 db = make_float4(b.x-mean,b.y-mean,b.z-mean,b.w-mean);
  float q = dot4(da,da) + dot4(db,db);
  q += __shfl_xor(q,1); q += __shfl_xor(q,2);
  float irs = rsqrtf(q*0.03125f + 1e-5f);
  float* drow = dst + r*36 + g*8;
  st4(drow,   make_float4(da.x*irs, da.y*irs, da.z*irs, da.w*irs));
  st4(drow+4, make_float4(db.x*irs, db.y*irs, db.z*irs, db.w*irs));
}

__device__ __forceinline__ void ln_rows64(const float* src, float* dst, int tid){
  int r = tid>>2, g = tid&3;
  const float* row = src + r*68 + g*16;
  float4 v0 = ld4(row), v1 = ld4(row+4), v2 = ld4(row+8), v3 = ld4(row+12);
  float s = v0.x+v0.y+v0.z+v0.w + v1.x+v1.y+v1.z+v1.w
          + v2.x+v2.y+v2.z+v2.w + v3.x+v3.y+v3.z+v3.w;
  s += __shfl_xor(s,1); s += __shfl_xor(s,2);
  float mean = s * 0.015625f;
  float4 d0 = make_float4(v0.x-mean,v0.y-mean,v0.z-mean,v0.w-mean);
  float4 d1 = make_float4(v1.x-mean,v1.y-mean,v1.z-mean,v1.w-mean);
  float4 d2 = make_float4(v2.x-mean,v2.y-mean,v2.z-mean,v2.w-mean);
  float4 d3 = make_float4(v3.x-mean,v3.y-mean,v3.z-mean,v3.w-mean);
  float q = dot4(d0,d0)+dot4(d1,d1)+dot4(d2,d2)+dot4(d3,d3);
  q += __shfl_xor(q,1); q += __shfl_xor(q,2);
  float irs = rsqrtf(q*0.015625f + 1e-5f);
  float* drow = dst + r*68 + g*16;
  st4(drow,    make_float4(d0.x*irs,d0.y*irs,d0.z*irs,d0.w*irs));
  st4(drow+4,  make_float4(d1.x*irs,d1.y*irs,d1.z*irs,d1.w*irs));
  st4(drow+8,  make_float4(d2.x*irs,d2.y*irs,d2.z*irs,d2.w*irs));
  st4(drow+12, make_float4(d3.x*irs,d3.y*irs,d3.z*irs,d3.w*irs));
}

// ============================ K_embed ======================================
__global__ __launch_bounds__(256, 3) void k_embed(
    const float* __restrict__ x, const float* __restrict__ fm,
    const int* __restrict__ ji,
    const float* __restrict__ stats,
    const float* __restrict__ bn_w, const float* __restrict__ bn_b,
    const float* __restrict__ e1w, const float* __restrict__ e1b,
    const float* __restrict__ e2w, const float* __restrict__ e2b,
    const float* __restrict__ c1w_g, const float* __restrict__ c1b_g,
    const float* __restrict__ c2w_g, const float* __restrict__ c2b_g,
    float* __restrict__ G_h, float* __restrict__ G_bias)
{
  const int n   = blockIdx.x;
  const int tid = threadIdx.x;
  const int njet = ji[n*2+1];
  const bool wact = ((tid>>6)<<4) < njet;

  __shared__ __align__(16) float SX[64*68];
  __shared__ __align__(16) float SY[64*68];   // scratch: PQ@0, C1O@448, CW@1472
  __shared__ __align__(16) float SW[4448];
  __shared__ float SSTAT[128];

  float* PQ  = SY;
  float* C1O = SY + 448;
  float* CW  = SY + 1472;

  if (tid < 64) {
    float mu = stats[tid], rs = stats[64+tid];
    float sc = rs * bn_w[tid];
    SSTAT[tid]      = sc;
    SSTAT[64+tid]   = bn_b[tid] - mu*sc;
  }
  if (tid < 64) {
    int p = tid;
    float e_  = fm[n*256 + p];
    float px_ = fm[n*256 + 64 + p];
    float py_ = fm[n*256 + 128 + p];
    float pz_ = fm[n*256 + 192 + p];
    float pt_ = sqrtf(px_*px_ + py_*py_ + 1e-8f);
    float y_  = 0.5f * logf((e_ + pz_ + 1e-8f) / (e_ - pz_ + 1e-8f));
    float ph_ = atan2f(py_, px_ + 1e-8f);
    if (ph_ < 0.f) ph_ += 6.283185307179586f;
    PQ[0*64+p]=e_; PQ[1*64+p]=px_; PQ[2*64+p]=py_; PQ[3*64+p]=pz_;
    PQ[4*64+p]=pt_; PQ[5*64+p]=y_; PQ[6*64+p]=ph_;
  }
  CW[tid] = c1w_g[tid];
  if (tid < 4)  CW[256+tid] = c1b_g[tid];
  if (tid < 64) CW[260+tid] = c2w_g[tid];
  if (tid < 4)  CW[324+tid] = c2b_g[tid];
  __syncthreads();

  // conv1 (stride4, k4) -> C1O [4][16][16]  (needs all 64 particles)
  {
    int ho = tid>>4, wo = tid&15;
    float a0=0.f,a1=0.f,a2=0.f,a3=0.f;
    #pragma unroll 1
    for (int kh=0; kh<4; kh++){
      int r = ho*4+kh;
      float er=PQ[r], pxr=PQ[64+r], pyr=PQ[128+r], pzr=PQ[192+r], ptr_=PQ[256+r], yr=PQ[320+r], phr=PQ[384+r];
      #pragma unroll
      for (int kw=0; kw<4; kw++){
        int c = wo*4+kw;
        if (r == c) continue;
        float ec=PQ[c], pxc=PQ[64+c], pyc=PQ[128+c], pzc=PQ[192+c], ptc=PQ[256+c], yc=PQ[320+c], phc=PQ[384+c];
        float dy = yr-yc, dp = phr-phc;
        float delta = sqrtf(fabsf(dy*dy + dp*dp));
        float pmin = fminf(ptr_, ptc);
        float kt = pmin * delta;
        float zz = pmin / (ptr_ + ptc + 1e-8f);
        float sx_ = pxr+pxc, sy_ = pyr+pyc, sz_ = pzr+pzc;
        float m2 = er*er + ec*ec - (sx_*sx_ + sy_*sy_ + sz_*sz_);
        int wb = kh*4+kw;
        a0 += delta*CW[0*64+wb] + kt*CW[0*64+16+wb] + zz*CW[0*64+32+wb] + m2*CW[0*64+48+wb];
        a1 += delta*CW[1*64+wb] + kt*CW[1*64+16+wb] + zz*CW[1*64+32+wb] + m2*CW[1*64+48+wb];
        a2 += delta*CW[2*64+wb] + kt*CW[2*64+16+wb] + zz*CW[2*64+32+wb] + m2*CW[2*64+48+wb];
        a3 += delta*CW[3*64+wb] + kt*CW[3*64+16+wb] + zz*CW[3*64+32+wb] + m2*CW[3*64+48+wb];
      }
    }
    C1O[0*256 + tid] = a0 + CW[256+0];
    C1O[1*256 + tid] = a1 + CW[256+1];
    C1O[2*256 + tid] = a2 + CW[256+2];
    C1O[3*256 + tid] = a3 + CW[256+3];
  }
  __syncthreads();

  // conv2 -> G_bias; BN-apply stage xc -> SX
  for (int idx = tid; idx < 324; idx += 256) {
    int co = idx/81, rem = idx%81, i = rem/9, j = rem%9;
    float s = CW[324+co];
    #pragma unroll
    for (int ci=0; ci<4; ci++){
      #pragma unroll
      for (int kh=0; kh<2; kh++){
        int ri = 2*i - 1 + kh;
        if (ri < 0 || ri >= 16) continue;
        #pragma unroll
        for (int kw=0; kw<2; kw++){
          int cj = 2*j - 1 + kw;
          if (cj < 0 || cj >= 16) continue;
          s += CW[260 + co*16 + ci*4 + kh*2 + kw] * C1O[ci*256 + ri*16 + cj];
        }
      }
    }
    G_bias[n*324 + idx] = s;
  }
  {
    int p4 = (tid & 15) * 4;
    float sc0 = SSTAT[p4], sc1 = SSTAT[p4+1], sc2 = SSTAT[p4+2], sc3 = SSTAT[p4+3];
    float sh0 = SSTAT[64+p4], sh1 = SSTAT[64+p4+1], sh2 = SSTAT[64+p4+2], sh3 = SSTAT[64+p4+3];
    for (int c = tid>>4; c < 64; c += 16) {
      float4 v = (c < 60) ? ld4(x + n*3840 + c*64 + p4) : ld4(fm + n*256 + (c-60)*64 + p4);
      st4(&SX[c*68 + p4], make_float4(v.x*sc0+sh0, v.y*sc1+sh1, v.z*sc2+sh2, v.w*sc3+sh3));
    }
  }
  __syncthreads();

  if (wact) ln_rows64(SX, SY, tid);
  for (int idx = tid; idx < 1024; idx += 256) st4(&SW[(idx>>4)*68 + (idx&15)*4], ld4(e1w + idx*4));
  if (tid < 64) SW[4352+tid] = e1b[tid];
  __syncthreads();

  // e1 GEMM 64x64 K=64 (row-skip) -> SX + gelu
  {
    int tg = tid>>4, og = tid&15;
    float acc[4][4];
    #pragma unroll
    for (int o=0;o<4;o++){ float b = SW[4352+o*16+og];
      #pragma unroll
      for (int i=0;i<4;i++) acc[i][o] = b; }
    if (wact) {
      #pragma unroll 2
      for (int j=0;j<64;j+=4){
        float4 av[4], wv[4];
        #pragma unroll
        for (int i=0;i<4;i++) av[i] = ld4(SY + (tg*4+i)*68 + j);
        #pragma unroll
        for (int o=0;o<4;o++) wv[o] = ld4(SW + (o*16+og)*68 + j);
        #pragma unroll
        for (int i=0;i<4;i++)
          #pragma unroll
          for (int o=0;o<4;o++) acc[i][o] += dot4(av[i], wv[o]);
      }
    }
    __syncthreads();
    if (wact) {
      #pragma unroll
      for (int i=0;i<4;i++)
        #pragma unroll
        for (int o=0;o<4;o++) SX[(tg*4+i)*68 + o*16+og] = geluf(acc[i][o]);
    }
  }
  __syncthreads();

  if (wact) ln_rows64(SX, SY, tid);
  for (int idx = tid; idx < 512; idx += 256) st4(&SW[(idx>>4)*68 + (idx&15)*4], ld4(e2w + idx*4));
  if (tid < 32) SW[4352+tid] = e2b[tid];
  __syncthreads();

  // e2 GEMM 64x32 K=64 (row-skip) -> G_h + gelu
  if (wact) {
    int tg = tid>>4, og = tid&15;
    float acc[4][2];
    #pragma unroll
    for (int o=0;o<2;o++){ float b = SW[4352+o*16+og];
      #pragma unroll
      for (int i=0;i<4;i++) acc[i][o] = b; }
    #pragma unroll 2
    for (int j=0;j<64;j+=4){
      float4 av[4], wv[2];
      #pragma unroll
      for (int i=0;i<4;i++) av[i] = ld4(SY + (tg*4+i)*68 + j);
      #pragma unroll
      for (int o=0;o<2;o++) wv[o] = ld4(SW + (o*16+og)*68 + j);
      #pragma unroll
      for (int i=0;i<4;i++)
        #pragma unroll
        for (int o=0;o<2;o++) acc[i][o] += dot4(av[i], wv[o]);
    }
    #pragma unroll
    for (int i=0;i<4;i++)
      #pragma unroll
      for (int o=0;o<2;o++) G_h[n*2048 + (tg*4+i)*32 + o*16+og] = geluf(acc[i][o]);
  }
}

// ============================ K_layer ======================================
// h lives in registers: thread (r=tid>>2, g=tid&3) owns h[r][g*8..g*8+7].
__global__ __launch_bounds__(256, 4) void k_layer(
    const int* __restrict__ ji,
    const float* __restrict__ in_w,  const float* __restrict__ in_b,
    const float* __restrict__ out_w, const float* __restrict__ out_b,
    const float* __restrict__ f1w,   const float* __restrict__ f1b,
    const float* __restrict__ f2w,   const float* __restrict__ f2b,
    const float* __restrict__ wres,
    float* __restrict__ G_h, const float* __restrict__ G_bias)
{
  const int n   = blockIdx.x;
  const int tid = threadIdx.x;
  const int njet = ji[n*2+1];
  const bool wact = ((tid>>6)<<4) < njet;
  const int r_ = tid>>2, g_ = tid&3;

  __shared__ __align__(16) float SX[64*36];
  __shared__ __align__(16) float SY[64*68];
  __shared__ __align__(16) float SW[3584];
  // total LDS = 9216 + 17408 + 14336 = 40960 B -> 4 blocks/CU

  float b9[9];
  {
    int hh = tid>>6, l = tid&63;
    if (l < 9) {
      #pragma unroll
      for (int j=0;j<9;j++) b9[j] = G_bias[n*324 + hh*81 + l*9 + j];
    } else {
      #pragma unroll
      for (int j=0;j<9;j++) b9[j] = 0.f;
    }
  }
  float4 h0 = make_float4(0,0,0,0), h1 = make_float4(0,0,0,0);
  if (wact) {
    h0 = ld4(G_h + n*2048 + r_*32 + g_*8);
    h1 = ld4(G_h + n*2048 + r_*32 + g_*8 + 4);
  }

  // L1: a = ln(h) from regs -> SX (row-skip); stage in_w + in_b
  if (wact) {
    float s = h0.x+h0.y+h0.z+h0.w + h1.x+h1.y+h1.z+h1.w;
    s += __shfl_xor(s,1); s += __shfl_xor(s,2);
    float mean = s * 0.03125f;
    float4 da = make_float4(h0.x-mean,h0.y-mean,h0.z-mean,h0.w-mean);
    float4 db = make_float4(h1.x-mean,h1.y-mean,h1.z-mean,h1.w-mean);
    float q = dot4(da,da) + dot4(db,db);
    q += __shfl_xor(q,1); q += __shfl_xor(q,2);
    float irs = rsqrtf(q*0.03125f + 1e-5f);
    st4(&SX[r_*36 + g_*8],   make_float4(da.x*irs, da.y*irs, da.z*irs, da.w*irs));
    st4(&SX[r_*36 + g_*8+4], make_float4(db.x*irs, db.y*irs, db.z*irs, db.w*irs));
  }
  for (int idx = tid; idx < 768; idx += 256) st4(&SW[(idx>>3)*36 + (idx&7)*4], ld4(in_w + idx*4));
  if (tid < 96) SW[3456+tid] = in_b[tid];
  __syncthreads();

  // L2: k,v GEMM (row-skip)
  if (wact) {
    int tg = tid>>4, og = tid&15;
    float acc[4][4];
    #pragma unroll
    for (int o=0;o<4;o++){ float b = SW[3456+32+o*16+og];
      #pragma unroll
      for (int i=0;i<4;i++) acc[i][o] = b; }
    #pragma unroll 2
    for (int j=0;j<32;j+=4){
      float4 av[4], wv[4];
      #pragma unroll
      for (int i=0;i<4;i++) av[i] = ld4(SX + (tg*4+i)*36 + j);
      #pragma unroll
      for (int o=0;o<4;o++) wv[o] = ld4(SW + (32+o*16+og)*36 + j);
      #pragma unroll
      for (int i=0;i<4;i++)
        #pragma unroll
        for (int o=0;o<4;o++) acc[i][o] += dot4(av[i], wv[o]);
    }
    #pragma unroll
    for (int i=0;i<4;i++)
      #pragma unroll
      for (int o=0;o<4;o++){
        int ew = 32 + o*16+og, t = tg*4+i;
        if (ew < 64) SY[(ew-32)*68 + t] = acc[i][o];
        else         SY[2176 + (ew-64)*68 + t] = acc[i][o];
      }
  }
  __syncthreads();

  // L3: attention (online softmax; chunks up to njet)
  float od[8];
  {
    int hh = tid>>6, l = tid&63;
    float qd[8];
    #pragma unroll
    for (int d=0;d<8;d++){
      int e = hh*8+d;
      float a_ = SW[3456+e];
      #pragma unroll
      for (int k=0;k<8;k++) a_ += dot4(ld4(SX + l*36 + k*4), ld4(SW + e*36 + k*4));
      qd[d] = a_ * 0.35355339059327373f;
    }
    float m = -3.4e38f, lsum = 0.f;
    #pragma unroll
    for (int d=0;d<8;d++) od[d] = 0.f;
    #pragma unroll 1
    for (int s0 = 0; s0 < njet; s0 += 16) {
      float sc[16];
      #pragma unroll
      for (int j=0;j<16;j++) sc[j]=0.f;
      #pragma unroll
      for (int d=0;d<8;d++){
        const float* kr = SY + (hh*8+d)*68 + s0;
        float qv = qd[d];
        #pragma unroll
        for (int j=0;j<16;j+=4){
          float4 kv4 = ld4(kr+j);
          sc[j]  +=qv*kv4.x; sc[j+1]+=qv*kv4.y;
          sc[j+2]+=qv*kv4.z; sc[j+3]+=qv*kv4.w;
        }
      }
      float cm = -3.4e38f;
      if (s0 != 0 && s0 + 16 <= njet) {
        #pragma unroll
        for (int j=0;j<16;j++) cm = fmaxf(cm, sc[j]);
      } else {
        #pragma unroll
        for (int j=0;j<16;j++){
          int s = s0+j;
          float a_ = sc[j];
          if (s0 == 0 && l < 9 && j < 9) a_ += b9[j];
          a_ = (s >= njet) ? -1000000000.0f : a_;
          sc[j] = a_;
          cm = fmaxf(cm, a_);
        }
      }
      float nm = fmaxf(m, cm);
      float corr = __expf(m - nm);
      lsum *= corr;
      #pragma unroll
      for (int d=0;d<8;d++) od[d] *= corr;
      #pragma unroll
      for (int j=0;j<16;j++){ sc[j] = __expf(sc[j]-nm); lsum += sc[j]; }
      #pragma unroll
      for (int d=0;d<8;d++){
        const float* vr = SY + 2176 + (hh*8+d)*68 + s0;
        float a_ = 0.f;
        #pragma unroll
        for (int j=0;j<16;j+=4){
          float4 vv = ld4(vr+j);
          a_ += sc[j]*vv.x + sc[j+1]*vv.y + sc[j+2]*vv.z + sc[j+3]*vv.w;
        }
        od[d] += a_;
      }
      m = nm;
    }
    float inv = 1.f/lsum;
    #pragma unroll
    for (int d=0;d<8;d++) od[d] *= inv;
  }
  __syncthreads();
  {
    int hh = tid>>6, l = tid&63;
    st4(&SX[l*36 + hh*8],     make_float4(od[0],od[1],od[2],od[3]));
    st4(&SX[l*36 + hh*8 + 4], make_float4(od[4],od[5],od[6],od[7]));
  }
  for (int idx = tid; idx < 256; idx += 256) st4(&SW[(idx>>3)*36 + (idx&7)*4], ld4(out_w + idx*4));
  if (tid < 32) SW[3456+tid] = out_b[tid];
  __syncthreads();

  // L4: out-proj (row-skip) -> SY stride 36
  if (wact) {
    int tg = tid>>4, og = tid&15;
    float acc[4][2];
    #pragma unroll
    for (int o=0;o<2;o++){ float b = SW[3456+o*16+og];
      #pragma unroll
      for (int i=0;i<4;i++) acc[i][o] = b; }
    #pragma unroll 2
    for (int j=0;j<32;j+=4){
      float4 av[4], wv[2];
      #pragma unroll
      for (int i=0;i<4;i++) av[i] = ld4(SX + (tg*4+i)*36 + j);
      #pragma unroll
      for (int o=0;o<2;o++) wv[o] = ld4(SW + (o*16+og)*36 + j);
      #pragma unroll
      for (int i=0;i<4;i++)
        #pragma unroll
        for (int o=0;o<2;o++) acc[i][o] += dot4(av[i], wv[o]);
    }
    #pragma unroll
    for (int i=0;i<4;i++)
      #pragma unroll
      for (int o=0;o<2;o++) SY[(tg*4+i)*36 + o*16+og] = acc[i][o];
  }
  __syncthreads();

  // L5+L6 fused: h += ln(y); a = ln(h) -> SX. (row-skip)  Then stage f1.
  if (wact) {
    const float* row = SY + r_*36 + g_*8;
    float4 a = ld4(row), b = ld4(row+4);
    float s = a.x+a.y+a.z+a.w + b.x+b.y+b.z+b.w;
    s += __shfl_xor(s,1); s += __shfl_xor(s,2);
    float mean = s * 0.03125f;
    float4 da = make_float4(a.x-mean,a.y-mean,a.z-mean,a.w-mean);
    float4 db = make_float4(b.x-mean,b.y-mean,b.z-mean,b.w-mean);
    float q = dot4(da,da) + dot4(db,db);
    q += __shfl_xor(q,1); q += __shfl_xor(q,2);
    float irs = rsqrtf(q*0.03125f + 1e-5f);
    h0 = make_float4(da.x*irs+h0.x, da.y*irs+h0.y, da.z*irs+h0.z, da.w*irs+h0.w);
    h1 = make_float4(db.x*irs+h1.x, db.y*irs+h1.y, db.z*irs+h1.z, db.w*irs+h1.w);
    // ln(h) -> SX
    float s2 = h0.x+h0.y+h0.z+h0.w + h1.x+h1.y+h1.z+h1.w;
    s2 += __shfl_xor(s2,1); s2 += __shfl_xor(s2,2);
    float mean2 = s2 * 0.03125f;
    float4 ea = make_float4(h0.x-mean2,h0.y-mean2,h0.z-mean2,h0.w-mean2);
    float4 eb = make_float4(h1.x-mean2,h1.y-mean2,h1.z-mean2,h1.w-mean2);
    float q2 = dot4(ea,ea) + dot4(eb,eb);
    q2 += __shfl_xor(q2,1); q2 += __shfl_xor(q2,2);
    float irs2 = rsqrtf(q2*0.03125f + 1e-5f);
    st4(&SX[r_*36 + g_*8],   make_float4(ea.x*irs2, ea.y*irs2, ea.z*irs2, ea.w*irs2));
    st4(&SX[r_*36 + g_*8+4], make_float4(eb.x*irs2, eb.y*irs2, eb.z*irs2, eb.w*irs2));
  }
  for (int idx = tid; idx < 512; idx += 256) st4(&SW[(idx>>3)*36 + (idx&7)*4], ld4(f1w + idx*4));
  if (tid < 64) SW[3456+tid] = f1b[tid];
  __syncthreads();

  // L7: g1 GEMM (row-skip) -> SY stride 68 + gelu
  if (wact) {
    int tg = tid>>4, og = tid&15;
    float acc[4][4];
    #pragma unroll
    for (int o=0;o<4;o++){ float b = SW[3456+o*16+og];
      #pragma unroll
      for (int i=0;i<4;i++) acc[i][o] = b; }
    #pragma unroll 2
    for (int j=0;j<32;j+=4){
      float4 av[4], wv[4];
      #pragma unroll
      for (int i=0;i<4;i++) av[i] = ld4(SX + (tg*4+i)*36 + j);
      #pragma unroll
      for (int o=0;o<4;o++) wv[o] = ld4(SW + (o*16+og)*36 + j);
      #pragma unroll
      for (int i=0;i<4;i++)
        #pragma unroll
        for (int o=0;o<4;o++) acc[i][o] += dot4(av[i], wv[o]);
    }
    #pragma unroll
    for (int i=0;i<4;i++)
      #pragma unroll
      for (int o=0;o<4;o++) SY[(tg*4+i)*68 + o*16+og] = geluf(acc[i][o]);
  }
  __syncthreads();

  // L8: ln64 in-place on SY (row-skip); stage f2 + bias + wres
  if (wact) {
    float* row = SY + r_*68 + g_*16;
    float4 v0 = ld4(row), v1 = ld4(row+4), v2 = ld4(row+8), v3 = ld4(row+12);
    float s = v0.x+v0.y+v0.z+v0.w + v1.x+v1.y+v1.z+v1.w
            + v2.x+v2.y+v2.z+v2.w + v3.x+v3.y+v3.z+v3.w;
    s += __shfl_xor(s,1); s += __shfl_xor(s,2);
    float mean = s * 0.015625f;
    float4 d0 = make_float4(v0.x-mean,v0.y-mean,v0.z-mean,v0.w-mean);
    float4 d1 = make_float4(v1.x-mean,v1.y-mean,v1.z-mean,v1.w-mean);
    float4 d2 = make_float4(v2.x-mean,v2.y-mean,v2.z-mean,v2.w-mean);
    float4 d3 = make_float4(v3.x-mean,v3.y-mean,v3.z-mean,v3.w-mean);
    float q = dot4(d0,d0)+dot4(d1,d1)+dot4(d2,d2)+dot4(d3,d3);
    q += __shfl_xor(q,1); q += __shfl_xor(q,2);
    float irs = rsqrtf(q*0.015625f + 1e-5f);
    st4(row,    make_float4(d0.x*irs,d0.y*irs,d0.z*irs,d0.w*irs));
    st4(row+4,  make_float4(d1.x*irs,d1.y*irs,d1.z*irs,d1.w*irs));
    st4(row+8,  make_float4(d2.x*irs,d2.y*irs,d2.z*irs,d2.w*irs));
    st4(row+12, make_float4(d3.x*irs,d3.y*irs,d3.z*irs,d3.w*irs));
  }
  for (int idx = tid; idx < 512; idx += 256) st4(&SW[(idx>>4)*68 + (idx&15)*4], ld4(f2w + idx*4));
  if (tid < 32){ SW[3456+tid] = f2b[tid]; SW[3488+tid] = wres[tid]; }
  __syncthreads();

  // L9: g2 GEMM (row-skip) -> raw acc into SX stride 36
  if (wact) {
    int tg = tid>>4, og = tid&15;
    float acc[4][2];
    #pragma unroll
    for (int o=0;o<2;o++){ float b = SW[3456+o*16+og];
      #pragma unroll
      for (int i=0;i<4;i++) acc[i][o] = b; }
    #pragma unroll 2
    for (int j=0;j<64;j+=4){
      float4 av[4], wv[2];
      #pragma unroll
      for (int i=0;i<4;i++) av[i] = ld4(SY + (tg*4+i)*68 + j);
      #pragma unroll
      for (int o=0;o<2;o++) wv[o] = ld4(SW + (o*16+og)*68 + j);
      #pragma unroll
      for (int i=0;i<4;i++)
        #pragma unroll
        for (int o=0;o<2;o++) acc[i][o] += dot4(av[i], wv[o]);
    }
    #pragma unroll
    for (int i=0;i<4;i++)
      #pragma unroll
      for (int o=0;o<2;o++) SX[(tg*4+i)*36 + o*16+og] = acc[i][o];
  }
  __syncthreads();

  // L10: h_new = g2 + wres*h -> G_h (reg mapping, coalesced)
  if (wact) {
    float4 a0 = ld4(&SX[r_*36 + g_*8]),  a1 = ld4(&SX[r_*36 + g_*8 + 4]);
    float4 w0 = ld4(&SW[3488 + g_*8]),   w1 = ld4(&SW[3488 + g_*8 + 4]);
    st4(G_h + n*2048 + r_*32 + g_*8,
        make_float4(a0.x + w0.x*h0.x, a0.y + w0.y*h0.y, a0.z + w0.z*h0.z, a0.w + w0.w*h0.w));
    st4(G_h + n*2048 + r_*32 + g_*8 + 4,
        make_float4(a1.x + w1.x*h1.x, a1.y + w1.y*h1.y, a1.z + w1.z*h1.z, a1.w + w1.w*h1.w));
  }
}

// ============================ K_cls ========================================
__global__ __launch_bounds__(256, 3) void k_cls(
    const int* __restrict__ ji,
    const float* __restrict__ cb_in_w, const float* __restrict__ cb_in_b,
    const float* __restrict__ cb_out_w, const float* __restrict__ cb_out_b,
    const float* __restrict__ cb_f1_w, const float* __restrict__ cb_f1_b,
    const float* __restrict__ cb_f2_w, const float* __restrict__ cb_f2_b,
    const float* __restrict__ cb_wres, const float* __restrict__ cb_cattn,
    const float* __restrict__ cls_tok, const float* __restrict__ norm_w, const float* __restrict__ norm_b,
    const float* __restrict__ m1w, const float* __restrict__ m1b,
    const float* __restrict__ mhw, const float* __restrict__ mhb,
    const float* __restrict__ mfw, const float* __restrict__ mfb,
    const float* __restrict__ G_h, float* __restrict__ out)
{
  const int n   = blockIdx.x;
  const int tid = threadIdx.x;
  const int njet = ji[n*2+1];
  const int nt16 = (njet + 15) & ~15;
  const bool wact = ((tid>>6)<<4) < njet;

  __shared__ __align__(16) float SX[64*36];
  __shared__ __align__(16) float SY[64*68];
  __shared__ __align__(16) float SW[3584];
  __shared__ __align__(16) float SV[320];
  __shared__ __align__(16) float csh[32];

  for (int idx = tid; idx < (nt16<<3); idx += 256) {
    float4 v = ld4(G_h + n*2048 + idx*4);
    int t = idx>>3, e = (idx&7)*4;
    st4(&SX[t*36 + e], v);
  }
  __syncthreads();

  if (wact) ln_rows32(SX, SX, tid);
  if (tid < 32) csh[tid] = cls_tok[tid];
  __syncthreads();

  #pragma unroll 1
  for (int cl = 0; cl < 2; cl++) {
    const float* iw = cb_in_w + cl*3072;
    const float* ib = cb_in_b + cl*96;

    if (tid < 32) {
      float v = csh[tid];
      float s = v;
      s += __shfl_xor(s,1); s += __shfl_xor(s,2); s += __shfl_xor(s,4); s += __shfl_xor(s,8); s += __shfl_xor(s,16);
      float mean = s * 0.03125f;
      float d = v - mean;
      float q = d*d;
      q += __shfl_xor(q,1); q += __shfl_xor(q,2); q += __shfl_xor(q,4); q += __shfl_xor(q,8); q += __shfl_xor(q,16);
      float irs = rsqrtf(q*0.03125f + 1e-5f);
      SV[tid] = d*irs;
    }
    for (int idx = tid; idx < 768; idx += 256) st4(&SW[(idx>>3)*36 + (idx&7)*4], ld4(iw + idx*4));
    if (tid < 96) SW[3456+tid] = ib[tid];
    __syncthreads();

    if (tid < 32) {
      int e = tid;
      float a_ = SW[3456+e];
      #pragma unroll
      for (int k=0;k<8;k++) a_ += dot4(ld4(&csh[k*4]), ld4(SW + e*36 + k*4));
      SV[32+e] = a_ * 0.35355339059327373f;
    }
    if (tid < 64) {
      int ew = 32 + tid;
      float a_ = SW[3456+ew];
      #pragma unroll
      for (int k=0;k<8;k++) a_ += dot4(ld4(SV + k*4), ld4(SW + ew*36 + k*4));
      if (ew < 64) SY[(ew-32)*68] = a_;
      else         SY[2176 + (ew-64)*68] = a_;
    }
    {
      int tg = tid>>4, og = tid&15;
      if (wact) {
        float acc[4][4];
        #pragma unroll
        for (int o=0;o<4;o++){ float b = SW[3456+32+o*16+og];
          #pragma unroll
          for (int i=0;i<4;i++) acc[i][o] = b; }
        #pragma unroll 2
        for (int j=0;j<32;j+=4){
          float4 av[4], wv[4];
          #pragma unroll
          for (int i=0;i<4;i++) av[i] = ld4(SX + (tg*4+i)*36 + j);
          #pragma unroll
          for (int o=0;o<4;o++) wv[o] = ld4(SW + (32+o*16+og)*36 + j);
          #pragma unroll
          for (int i=0;i<4;i++)
            #pragma unroll
            for (int o=0;o<4;o++) acc[i][o] += dot4(av[i], wv[o]);
        }
        #pragma unroll
        for (int i=0;i<4;i++)
          #pragma unroll
          for (int o=0;o<4;o++){
            int ew = 32 + o*16+og, s = tg*4+i + 1;
            if (ew < 64) SY[(ew-32)*68 + s] = acc[i][o];
            else         SY[2176 + (ew-64)*68 + s] = acc[i][o];
          }
      } else {
        #pragma unroll
        for (int i=0;i<4;i++)
          #pragma unroll
          for (int o=0;o<4;o++){
            int ew = 32 + o*16+og, s = tg*4+i + 1;
            if (ew < 64) SY[(ew-32)*68 + s] = 0.f;
            else         SY[2176 + (ew-64)*68 + s] = 0.f;
          }
      }
    }
    __syncthreads();

    {
      int hh = tid>>6, l = tid&63;
      float q8[8];
      #pragma unroll
      for (int d=0;d<8;d++) q8[d] = SV[32 + hh*8 + d];
      float sc_ = 0.f;
      #pragma unroll
      for (int d=0;d<8;d++) sc_ += q8[d]*SY[(hh*8+d)*68 + l];
      if (l > 0 && (l-1) >= njet) sc_ = -1000000000.0f;
      float sc64 = 0.f;
      if (l == 0){
        #pragma unroll
        for (int d=0;d<8;d++) sc64 += q8[d]*SY[(hh*8+d)*68 + 64];
        if (63 >= njet) sc64 = -1000000000.0f;
      }
      float mx = sc_;
      if (l == 0) mx = fmaxf(mx, sc64);
      mx = fmaxf(mx, __shfl_xor(mx,1));  mx = fmaxf(mx, __shfl_xor(mx,2));
      mx = fmaxf(mx, __shfl_xor(mx,4));  mx = fmaxf(mx, __shfl_xor(mx,8));
      mx = fmaxf(mx, __shfl_xor(mx,16)); mx = fmaxf(mx, __shfl_xor(mx,32));
      float p   = __expf(sc_ - mx);
      float p64 = (l==0) ? __expf(sc64 - mx) : 0.f;
      float ssum = p + p64;
      ssum += __shfl_xor(ssum,1); ssum += __shfl_xor(ssum,2); ssum += __shfl_xor(ssum,4);
      ssum += __shfl_xor(ssum,8); ssum += __shfl_xor(ssum,16); ssum += __shfl_xor(ssum,32);
      float inv = 1.f/ssum;
      #pragma unroll
      for (int d=0;d<8;d++){
        float term = p * SY[2176 + (hh*8+d)*68 + l];
        if (l == 0) term += p64 * SY[2176 + (hh*8+d)*68 + 64];
        term += __shfl_xor(term,1); term += __shfl_xor(term,2); term += __shfl_xor(term,4);
        term += __shfl_xor(term,8); term += __shfl_xor(term,16); term += __shfl_xor(term,32);
        if (l == 0) SV[64 + hh*8 + d] = term*inv;
      }
    }
    __syncthreads();

    if (tid < 32) {
      int e = tid;
      const float* wrow = cb_out_w + (cl*32 + e)*32;
      float a_ = cb_out_b[cl*32 + e];
      #pragma unroll
      for (int j=0;j<32;j++) a_ += SV[64+j]*wrow[j];
      float ca = cb_cattn[cl*4 + (e>>3)];
      SV[96 + (e&7)*4 + (e>>3)] = a_*ca;
    }
    if (tid < 32) {
      float v = SV[96+tid];
      float s = v;
      s += __shfl_xor(s,1); s += __shfl_xor(s,2); s += __shfl_xor(s,4); s += __shfl_xor(s,8); s += __shfl_xor(s,16);
      float mean = s * 0.03125f;
      float d = v - mean;
      float q = d*d;
      q += __shfl_xor(q,1); q += __shfl_xor(q,2); q += __shfl_xor(q,4); q += __shfl_xor(q,8); q += __shfl_xor(q,16);
      float irs = rsqrtf(q*0.03125f + 1e-5f);
      csh[tid] = d*irs + csh[tid];
    }
    if (tid < 32) {
      float v = csh[tid];
      float s = v;
      s += __shfl_xor(s,1); s += __shfl_xor(s,2); s += __shfl_xor(s,4); s += __shfl_xor(s,8); s += __shfl_xor(s,16);
      float mean = s * 0.03125f;
      float d = v - mean;
      float q = d*d;
      q += __shfl_xor(q,1); q += __shfl_xor(q,2); q += __shfl_xor(q,4); q += __shfl_xor(q,8); q += __shfl_xor(q,16);
      float irs = rsqrtf(q*0.03125f + 1e-5f);
      SV[tid] = d*irs;
    }
    if (tid < 64) {
      int o = tid;
      const float* wrow = cb_f1_w + (cl*64+o)*32;
      float a_ = cb_f1_b[cl*64+o];
      #pragma unroll
      for (int j=0;j<32;j++) a_ += SV[j]*wrow[j];
      SV[128+o] = geluf(a_);
    }
    if (tid < 64) {
      float v = SV[128+tid];
      float s = v;
      s += __shfl_xor(s,1); s += __shfl_xor(s,2); s += __shfl_xor(s,4); s += __shfl_xor(s,8);
      s += __shfl_xor(s,16); s += __shfl_xor(s,32);
      float mean = s * 0.015625f;
      float d = v - mean;
      float q = d*d;
      q += __shfl_xor(q,1); q += __shfl_xor(q,2); q += __shfl_xor(q,4); q += __shfl_xor(q,8);
      q += __shfl_xor(q,16); q += __shfl_xor(q,32);
      float irs = rsqrtf(q*0.015625f + 1e-5f);
      SV[192+tid] = d*irs;
    }
    if (tid < 32) {
      int e = tid;
      const float* wrow = cb_f2_w + (cl*32+e)*64;
      float a_ = cb_f2_b[cl*32+e];
      #pragma unroll
      for (int j=0;j<64;j++) a_ += SV[192+j]*wrow[j];
      csh[e] = a_ + cb_wres[cl*32+e]*csh[e];
    }
  }

  // head: wave 0 only
  if (tid < 32) {
    float v = csh[tid];
    float s = v;
    s += __shfl_xor(s,1); s += __shfl_xor(s,2); s += __shfl_xor(s,4); s += __shfl_xor(s,8); s += __shfl_xor(s,16);
    float mean = s * 0.03125f;
    float d = v - mean;
    float q = d*d;
    q += __shfl_xor(q,1); q += __shfl_xor(q,2); q += __shfl_xor(q,4); q += __shfl_xor(q,8); q += __shfl_xor(q,16);
    float irs = rsqrtf(q*0.03125f + 1e-5f);
    SV[tid] = d*irs*norm_w[tid] + norm_b[tid];
  }
  if (tid < 32) {
    float a_ = m1b[tid];
    const float* wrow = m1w + tid*32;
    #pragma unroll
    for (int j=0;j<32;j++) a_ += SV[j]*wrow[j];
    SV[64+tid] = fmaxf(a_, 0.f);
  }
  if (tid < 32) {
    float a_ = mhb[tid];
    const float* wrow = mhw + tid*32;
    #pragma unroll
    for (int j=0;j<32;j++) a_ += SV[64+j]*wrow[j];
    SV[128+tid] = fmaxf(a_, 0.f);
  }
  if (tid == 0) {
    float a_ = mfb[0];
    #pragma unroll
    for (int j=0;j<32;j++) a_ += SV[128+j]*mfw[j];
    out[n] = 1.f/(1.f + expf(-a_));
  }
}

// ---------------------------------------------------------------------------
extern "C" void kernel_launch(void* const* d_in, const int* in_sizes, int n_in,
                              void* d_out, int out_size, void* d_ws, size_t ws_size,
                              hipStream_t stream) {
  (void)in_sizes; (void)n_in; (void)out_size; (void)ws_size;
  const float* x     = (const float*)d_in[0];
  const float* fm    = (const float*)d_in[1];
  const int*   ji    = (const int*)  d_in[2];
  const float* bn_w  = (const float*)d_in[3];
  const float* bn_b  = (const float*)d_in[4];
  const float* e1w   = (const float*)d_in[5];
  const float* e1b   = (const float*)d_in[6];
  const float* e2w   = (const float*)d_in[7];
  const float* e2b   = (const float*)d_in[8];
  const float* c1w   = (const float*)d_in[9];
  const float* c1b   = (const float*)d_in[10];
  const float* c2w   = (const float*)d_in[11];
  const float* c2b   = (const float*)d_in[12];
  const float* pb_in_w  = (const float*)d_in[13];
  const float* pb_in_b  = (const float*)d_in[14];
  const float* pb_out_w = (const float*)d_in[15];
  const float* pb_out_b = (const float*)d_in[16];
  const float* pb_f1_w  = (const float*)d_in[17];
  const float* pb_f1_b  = (const float*)d_in[18];
  const float* pb_f2_w  = (const float*)d_in[19];
  const float* pb_f2_b  = (const float*)d_in[20];
  const float* pb_wres  = (const float*)d_in[21];
  const float* cb_in_w  = (const float*)d_in[22];
  const float* cb_in_b  = (const float*)d_in[23];
  const float* cb_out_w = (const float*)d_in[24];
  const float* cb_out_b = (const float*)d_in[25];
  const float* cb_f1_w  = (const float*)d_in[26];
  const float* cb_f1_b  = (const float*)d_in[27];
  const float* cb_f2_w  = (const float*)d_in[28];
  const float* cb_f2_b  = (const float*)d_in[29];
  const float* cb_wres  = (const float*)d_in[30];
  const float* cb_cattn = (const float*)d_in[31];
  const float* cls_tok  = (const float*)d_in[32];
  const float* norm_w   = (const float*)d_in[33];
  const float* norm_b   = (const float*)d_in[34];
  const float* m1w      = (const float*)d_in[35];
  const float* m1b      = (const float*)d_in[36];
  const float* mhw      = (const float*)d_in[37];
  const float* mhb      = (const float*)d_in[38];
  const float* mfw      = (const float*)d_in[39];
  const float* mfb      = (const float*)d_in[40];

  float* part   = (float*)d_ws;                 // 32768 floats
  float* stats  = part + 32768;                 // 128 floats
  float* G_h    = part + 40960;                 // 2048*2048 floats
  float* G_bias = G_h + 2048*2048;              // 2048*324 floats

  bn_stats_partial<<<256, 256, 0, stream>>>(x, fm, part);
  bn_stats_final<<<1, 64, 0, stream>>>(part, stats);
  k_embed<<<2048, 256, 0, stream>>>(x, fm, ji, stats, bn_w, bn_b, e1w, e1b, e2w, e2b,
                                    c1w, c1b, c2w, c2b, G_h, G_bias);
  for (int li = 0; li < 4; li++) {
    k_layer<<<2048, 256, 0, stream>>>(ji,
        pb_in_w + li*3072, pb_in_b + li*96,
        pb_out_w + li*1024, pb_out_b + li*32,
        pb_f1_w + li*2048, pb_f1_b + li*64,
        pb_f2_w + li*2048, pb_f2_b + li*32,
        pb_wres + li*32, G_h, G_bias);
  }
  k_cls<<<2048, 256, 0, stream>>>(ji, cb_in_w, cb_in_b, cb_out_w, cb_out_b,
                                  cb_f1_w, cb_f1_b, cb_f2_w, cb_f2_b,
                                  cb_wres, cb_cattn, cls_tok, norm_w, norm_b,
                                  m1w, m1b, mhw, mhb, mfw, mfb, G_h, (float*)d_out);
}